// Round 11
// baseline (526.272 us; speedup 1.0000x reference)
//
#include <hip/hip_runtime.h>
#include <math.h>

// ---------------- problem constants ----------------
#define TSTEPS 64
#define NSEQ   32
#define FH     40
#define FW     160

// ---------------- workspace layout (float units) ----------------
#define OFF_XGB    0u            // [2][64 t][256 unit][32 n][4 gate] bf16, x1024
#define OFF_RNNB   2097152u      // [2048 tn][1024] bf16
#define OFF_W12B   3145728u      // W_ih l1 bf16, row-permuted unit*4+gate, [2048][1024]
#define OFF_W22B   4194304u      // W_ih l2 bf16 permuted [2048][256]
#define OFF_WE1B   4456448u      // W_emb1 bf16 [256][512], COLUMNS pi-permuted
#define OFF_WE2B   4521984u      // W_emb2 bf16 [12][512], COLUMNS pi-permuted
#define OFF_PB1    4525056u      // combined permuted bias l1 [2048] f32
#define OFF_PB2    4527104u      // combined permuted bias l2 [2048] f32
#define OFF_W8L1F  4529152u      // W_hh fp8 (x64) k-permuted [1024][256]
#define OFF_W8L1B  4594688u
#define OFF_W8L2F  4660224u
#define OFF_W8L2B  4725760u
#define OFF_HCB1   4791296u      // hcat1 bf16 [2048][512] (pi-permuted cols)
#define OFF_HCB2   5315584u
#define OFF_H1B    5839872u      // h1 bf16 [2048][256]
#define OFF_PREDS  6102016u      // [2048][12] f32

typedef __attribute__((ext_vector_type(8))) short short8;
typedef __attribute__((ext_vector_type(4))) float f32x4;
typedef __attribute__((ext_vector_type(4))) unsigned short ushort4v;
typedef __attribute__((ext_vector_type(4))) unsigned uint4v;

static __device__ inline unsigned short bf16c(float x) {
  union { float f; unsigned u; } v; v.f = x;
  unsigned r = v.u + 0x7fff + ((v.u >> 16) & 1);   // RNE
  return (unsigned short)(r >> 16);
}
static __device__ inline float b2f(unsigned short u) {
  union { unsigned u; float f; } v; v.u = ((unsigned)u) << 16;
  return v.f;
}
// pack 2 f32 -> u32 of 2 bf16 (hardware cvt_pk, RNE)
static __device__ inline unsigned pk_bf16(float lo, float hi) {
  unsigned r;
  asm("v_cvt_pk_bf16_f32 %0, %1, %2" : "=v"(r) : "v"(lo), "v"(hi));
  return r;
}
// f32 -> fp8 e4m3fn (OCP): RNE, saturate, flush subnormals
static __device__ inline unsigned char fp8c(float x) {
  union { float f; unsigned u; } v; v.f = x;
  unsigned s = (v.u >> 24) & 0x80;
  float ax = fabsf(x);
  if (ax < 0.015625f) return (unsigned char)s;
  if (ax >= 448.0f) return (unsigned char)(s | 0x7e);
  unsigned e = (v.u >> 23) & 0xff;
  unsigned m = v.u & 0x7fffff;
  unsigned r = m + 0x7ffff + ((m >> 20) & 1);
  if (r >> 23) { e += 1; r = 0; }
  unsigned m3 = (r >> 20) & 7;
  int ee = (int)e - 127 + 7;
  if (ee > 15) return (unsigned char)(s | 0x7e);
  return (unsigned char)(s | (ee << 3) | m3);
}
static __device__ inline unsigned pk4_fp8(float a, float b, float c, float d) {
#if __has_builtin(__builtin_amdgcn_cvt_pk_fp8_f32)
  int r = __builtin_amdgcn_cvt_pk_fp8_f32(a, b, 0, false);
  r = __builtin_amdgcn_cvt_pk_fp8_f32(c, d, r, true);
  return (unsigned)r;
#else
  return (unsigned)fp8c(a) | ((unsigned)fp8c(b) << 8)
       | ((unsigned)fp8c(c) << 16) | ((unsigned)fp8c(d) << 24);
#endif
}

// ---------------- single prep kernel ----------------
// blocks: [0,2048) l1 W_ih bf16 perm | [2048,2560) l2 W_ih | [2560,2688) we1 pi-col |
// [2688,2694) we2 pi-col | [2694,3718) fp8 W_hh x4 | [3718,3726) pb1 | [3726,3734) pb2
__global__ __launch_bounds__(256) void prep_kernel(
    const float* __restrict__ w1f, const float* __restrict__ w1b,
    const float* __restrict__ w2f, const float* __restrict__ w2b,
    const float* __restrict__ we1, const float* __restrict__ we2,
    const float* __restrict__ wh1f, const float* __restrict__ wh1b,
    const float* __restrict__ wh2f, const float* __restrict__ wh2b,
    const float* __restrict__ b1fi, const float* __restrict__ b1fh,
    const float* __restrict__ b1bi, const float* __restrict__ b1bh,
    const float* __restrict__ b2fi, const float* __restrict__ b2fh,
    const float* __restrict__ b2bi, const float* __restrict__ b2bh,
    unsigned short* __restrict__ w12b, unsigned short* __restrict__ w22b,
    unsigned short* __restrict__ we1o, unsigned short* __restrict__ we2o,
    unsigned char* __restrict__ o8l1f, unsigned char* __restrict__ o8l1b,
    unsigned char* __restrict__ o8l2f, unsigned char* __restrict__ o8l2b,
    float* __restrict__ pb1, float* __restrict__ pb2) {
  int b = blockIdx.x, tid = threadIdx.x;
  if (b < 2048) {
    const float* src = (b < 1024) ? w1f : w1b;
    unsigned short* dst = w12b + (size_t)((b < 1024) ? 0 : 1048576);
    int i = (b & 1023) * 256 + tid;
    int row = i >> 8, c4 = i & 255;
    int orow = (row & 255) * 4 + (row >> 8);   // gate*256+unit -> unit*4+gate
    float4 v = ((const float4*)src)[i];
    ushort4v o; o[0]=bf16c(v.x); o[1]=bf16c(v.y); o[2]=bf16c(v.z); o[3]=bf16c(v.w);
    *(ushort4v*)(dst + (size_t)orow * 1024 + c4 * 4) = o;
  } else if (b < 2560) {
    int bb = b - 2048;
    const float* src = (bb < 256) ? w2f : w2b;
    unsigned short* dst = w22b + (size_t)((bb < 256) ? 0 : 262144);
    int i = (bb & 255) * 256 + tid;
    int row = i >> 6, c4 = i & 63;
    int orow = (row & 255) * 4 + (row >> 8);
    float4 v = ((const float4*)src)[i];
    ushort4v o; o[0]=bf16c(v.x); o[1]=bf16c(v.y); o[2]=bf16c(v.z); o[3]=bf16c(v.w);
    *(ushort4v*)(dst + (size_t)orow * 256 + c4 * 4) = o;
  } else if (b < 2688) {
    // we1: out[j][d*256 + k] = in[j][d*256 + invpi(k)], invpi(k) = (k>>6) + (k&63)*4
    int i = (b - 2560) * 256 + tid;            // 0..32767 output quads
    int j = i >> 7, c4 = (i & 127) * 4;
    ushort4v o;
#pragma unroll
    for (int q = 0; q < 4; ++q) {
      int c = c4 + q;
      int d = c >> 8, k = c & 255;
      int u = (k >> 6) + (k & 63) * 4;
      o[q] = bf16c(we1[(size_t)j * 512 + d * 256 + u]);
    }
    ((ushort4v*)we1o)[i] = o;
  } else if (b < 2694) {
    int i = (b - 2688) * 256 + tid;            // 0..1535 quads (12x512)
    int j = i >> 7, c4 = (i & 127) * 4;
    ushort4v o;
#pragma unroll
    for (int q = 0; q < 4; ++q) {
      int c = c4 + q;
      int d = c >> 8, k = c & 255;
      int u = (k >> 6) + (k & 63) * 4;
      o[q] = bf16c(we2[(size_t)j * 512 + d * 256 + u]);
    }
    ((ushort4v*)we2o)[i] = o;
  } else if (b < 3718) {
    int bb = b - 2694;
    int which = bb >> 8;
    const float* src = (which == 0) ? wh1f : (which == 1) ? wh1b
                     : (which == 2) ? wh2f : wh2b;
    unsigned char* dst = (which == 0) ? o8l1f : (which == 1) ? o8l1b
                       : (which == 2) ? o8l2f : o8l2b;
    int idx = (bb & 255) * 256 + tid;
    int row = idx >> 6, k4 = (idx & 63) * 4;
    const float* r = src + (size_t)row * 256;
    unsigned o = 0;
#pragma unroll
    for (int j = 0; j < 4; ++j) {
      int kp = k4 + j;
      int u = (kp >> 6) + (kp & 63) * 4;       // inverse k-permute
      o |= ((unsigned)fp8c(r[u] * 64.0f)) << (8 * j);
    }
    ((unsigned*)dst)[idx] = o;
  } else if (b < 3726) {
    int m = (b - 3718) * 256 + tid;
    int dirq = m >> 10, mloc = m & 1023;
    int r = (mloc & 3) * 256 + (mloc >> 2);
    pb1[m] = dirq ? (b1bi[r] + b1bh[r]) : (b1fi[r] + b1fh[r]);
  } else {
    int m = (b - 3726) * 256 + tid;
    int dirq = m >> 10, mloc = m & 1023;
    int r = (mloc & 3) * 256 + (mloc >> 2);
    pb2[m] = dirq ? (b2bi[r] + b2bh[r]) : (b2fi[r] + b2fh[r]);
  }
}

// ---------------- ROI max pool -> rnn bf16 [t*32+n][c*2+ph] ----------------
__global__ __launch_bounds__(256) void roi_pool_kernel(
    const float* __restrict__ feat, const float* __restrict__ rois,
    unsigned short* __restrict__ rnn) {
  int n  = blockIdx.x;
  int cg = blockIdx.y;
  int tid = threadIdx.x;
  int pw = tid & 63, ph = (tid >> 6) & 1, cl = tid >> 7;
  int c = cg * 2 + cl;

  const float* r = rois + n * 5;
  int bi = (int)r[0];
  int x1 = (int)rintf(r[1] * (float)FW);
  int y1 = (int)rintf(r[2] * (float)FH);
  int x2 = (int)rintf(r[3] * (float)FW);
  int y2 = (int)rintf(r[4] * (float)FH);
  float rw = fmaxf((float)(x2 - x1 + 1), 1.0f);
  float rh = fmaxf((float)(y2 - y1 + 1), 1.0f);
  float bin_h = rh * 0.5f;
  float bin_w = rw * (1.0f / 64.0f);

  int hs = min(max((int)floorf((float)ph * bin_h) + y1, 0), FH);
  int he = min(max((int)ceilf((float)(ph + 1) * bin_h) + y1, 0), FH);
  int wst = min(max((int)floorf((float)pw * bin_w) + x1, 0), FW);
  int wen = min(max((int)ceilf((float)(pw + 1) * bin_w) + x1, 0), FW);

  float m = -1e30f;
  bool nonempty = (hs < he) && (wst < wen);
  const float* f = feat + ((size_t)bi * 512 + c) * (FH * FW);
  for (int h = hs; h < he; ++h) {
    const float* fr = f + h * FW;
    for (int w = wst; w < wen; ++w) m = fmaxf(m, fr[w]);
  }
  float out = nonempty ? m : 0.0f;
  rnn[((size_t)pw * NSEQ + n) * 1024 + c * 2 + ph] = bf16c(out);
}

// ---------------- bf16 MFMA GEMM ----------------
// mode 0: Cf[m*N+n] f32; mode 1: Cb[m*N+n] bf16;
// mode 5: xg write: Cb[dir*2097152 + ((t*256+unit)*32+n)*4 + gate] = bf16(v*1024)
#define GPITCH 40
__global__ __launch_bounds__(256) void gemm_bf16(
    const unsigned short* __restrict__ A, const unsigned short* __restrict__ B,
    float* __restrict__ Cf, unsigned short* __restrict__ Cb,
    int M, int N, int K,
    const float* __restrict__ bm1, const float* __restrict__ bn, int mode) {
  __shared__ unsigned short Al[128 * GPITCH];
  __shared__ unsigned short Bl[128 * GPITCH];
  int m0 = blockIdx.y * 128, n0 = blockIdx.x * 128;
  int tid = threadIdx.x;
  int wid = tid >> 6, l = tid & 63, ln15 = l & 15, kg = l >> 4;
  int wm = wid >> 1, wn = wid & 1;

  f32x4 acc[4][4];
#pragma unroll
  for (int i = 0; i < 4; ++i)
#pragma unroll
    for (int j = 0; j < 4; ++j)
#pragma unroll
      for (int q = 0; q < 4; ++q) acc[i][j][q] = 0.0f;

  for (int k0 = 0; k0 < K; k0 += 32) {
#pragma unroll
    for (int it = 0; it < 2; ++it) {
      int chunk = tid + it * 256;
      int row = chunk >> 2, part = chunk & 3;
      short8 va = *(const short8*)(A + (size_t)(m0 + row) * K + k0 + part * 8);
      *(short8*)(Al + row * GPITCH + part * 8) = va;
      short8 vb;
      if (n0 + row < N) {
        vb = *(const short8*)(B + (size_t)(n0 + row) * K + k0 + part * 8);
      } else {
#pragma unroll
        for (int q = 0; q < 8; ++q) vb[q] = 0;
      }
      *(short8*)(Bl + row * GPITCH + part * 8) = vb;
    }
    __syncthreads();

    short8 a[4], b[4];
#pragma unroll
    for (int mt = 0; mt < 4; ++mt)
      a[mt] = *(const short8*)(Al + (wm * 64 + mt * 16 + ln15) * GPITCH + kg * 8);
#pragma unroll
    for (int nt = 0; nt < 4; ++nt)
      b[nt] = *(const short8*)(Bl + (wn * 64 + nt * 16 + ln15) * GPITCH + kg * 8);
#pragma unroll
    for (int mt = 0; mt < 4; ++mt)
#pragma unroll
      for (int nt = 0; nt < 4; ++nt)
        acc[mt][nt] = __builtin_amdgcn_mfma_f32_16x16x32_bf16(a[mt], b[nt], acc[mt][nt], 0, 0, 0);
    __syncthreads();
  }

  if (mode == 5) {
#pragma unroll
    for (int mt = 0; mt < 4; ++mt) {
      int mbase = m0 + wm * 64 + mt * 16 + kg * 4;
      f32x4 pbv = *(const f32x4*)(bm1 + mbase);
      int dirq = mbase >> 10;
      int unit = (mbase & 1023) >> 2;
#pragma unroll
      for (int nt = 0; nt < 4; ++nt) {
        int col = n0 + wn * 64 + nt * 16 + ln15;
        int t = col >> 5, n = col & 31;
        ushort4v q;
#pragma unroll
        for (int j = 0; j < 4; ++j)
          q[j] = bf16c((acc[mt][nt][j] + pbv[j]) * 1024.0f);
        *(ushort4v*)(Cb + (size_t)dirq * 2097152u + ((t << 8) + unit) * 128 + n * 4) = q;
      }
    }
    return;
  }

#pragma unroll
  for (int mt = 0; mt < 4; ++mt) {
#pragma unroll
    for (int j = 0; j < 4; ++j) {
      int m = m0 + wm * 64 + mt * 16 + kg * 4 + j;
      float bmv = bm1 ? bm1[m] : 0.0f;
#pragma unroll
      for (int nt = 0; nt < 4; ++nt) {
        int n = n0 + wn * 64 + nt * 16 + ln15;
        if (n < N) {
          float v = acc[mt][nt][j] + bmv;
          if (bn) v += bn[n];
          if (mode == 1) Cb[(size_t)m * N + n] = bf16c(v);
          else Cf[(size_t)m * N + n] = v;
        }
      }
    }
  }
}

// ---------------- persistent BiLSTM layer v10: 8 waves, light barrier ----------
// Grid 4 blocks: dir = blk>>1, batch-half = blk&1 (16 n). 512 thr = 8 waves,
// 8 mt/wave. Deferred hcat store (issued top of next iter). Barrier drains
// LDS ONLY (s_waitcnt lgkmcnt(0) + raw s_barrier): global stores/loads span
// the barrier instead of being vmcnt(0)-drained every step.
__global__ __launch_bounds__(512, 2) void lstm_layer10(
    const unsigned short* __restrict__ xgb,  // [dir][t][unit][n][gate] bf16, x1024
    const unsigned char* __restrict__ w8fw,  // [1024][256] fp8 (x64), k-permuted
    const unsigned char* __restrict__ w8bw,
    unsigned short* __restrict__ hcatb) {    // [64][32][512] bf16, pi-cols
  const int dir = blockIdx.x >> 1;
  const int nbase = (blockIdx.x & 1) * 16;
  const int tid = threadIdx.x;
  const int w = tid >> 6;
  const int l = tid & 63;
  const int ln15 = l & 15;
  const int kg = l >> 4;
  const int u_wave = w * 32;

  __shared__ unsigned char h8[2][16][256];   // fp8 h (x16), k-permuted + swizzled

  const unsigned char* W8 = dir ? w8bw : w8fw;

  unsigned long long afrag[8][8];
  {
    int gate = ln15 & 3, du = ln15 >> 2;
#pragma unroll
    for (int mt = 0; mt < 8; ++mt) {
      const unsigned char* wr = W8 + (size_t)((gate << 8) + u_wave + mt * 4 + du) * 256;
#pragma unroll
      for (int kc = 0; kc < 8; ++kc)
        afrag[mt][kc] = *(const unsigned long long*)(wr + kc * 32 + kg * 8);
    }
  }

  const unsigned short* xgd = xgb + (size_t)dir * 2097152u;
  const int lane_off = (nbase + ln15) * 4;
  float cst[8] = {0.f, 0.f, 0.f, 0.f, 0.f, 0.f, 0.f, 0.f};
  f32x4 acc[8];
  ushort4v xnext[8];
  uint4v hpend;                      // previous step's 8 h as bf16 (deferred store)
  int tpend = 0;

  {
    int t0 = dir ? 63 : 0;
    const unsigned short* xb = xgd + (size_t)t0 * 32768 + lane_off;
#pragma unroll
    for (int mt = 0; mt < 8; ++mt)
      xnext[mt] = *(const ushort4v*)(xb + (u_wave + mt * 4 + kg) * 128);
#pragma unroll
    for (int mt = 0; mt < 8; ++mt)
#pragma unroll
      for (int j = 0; j < 4; ++j) acc[mt][j] = b2f(xnext[mt][j]);
  }

  const int swzw = (ln15 & 7) << 4;
  const int myslot = kg * 64 + w * 8;        // pi-slot of this lane's 8 h (contig mt)
  unsigned short* hc_lane = hcatb + (size_t)(nbase + ln15) * 512 + dir * 256 + myslot;
  const float kNI = -1.442695041f / 1024.0f;  // -log2e/1024
  const float kP2 = 2.885390082f / 1024.0f;   // +2*log2e/1024
  const float k2L = 2.885390082f;             // 2*log2e

  for (int s = 0; s < TSTEPS; ++s) {
    const int t = dir ? (63 - s) : s;
    const int p = s & 1;

    // A0) deferred hcat store of previous step's h (drains during MFMA+cell)
    if (s > 0)
      *(uint4v*)(hc_lane + (size_t)tpend * 16384) = hpend;

    // A) issue next-step xg loads
    if (s < TSTEPS - 1) {
      int tn2 = dir ? (t - 1) : (t + 1);
      const unsigned short* xb = xgd + (size_t)tn2 * 32768 + lane_off;
#pragma unroll
      for (int mt = 0; mt < 8; ++mt)
        xnext[mt] = *(const ushort4v*)(xb + (u_wave + mt * 4 + kg) * 128);
    }

    // B) MFMA: acc += (64*W)(16*h)
    if (s > 0) {
      const unsigned char* hrow = &h8[p][ln15][0];
#pragma unroll
      for (int kc = 0; kc < 8; ++kc) {
        unsigned long long hb =
            *(const unsigned long long*)(hrow + ((kc * 32 + kg * 8) ^ swzw));
#pragma unroll
        for (int mt = 0; mt < 8; ++mt)
          acc[mt] = __builtin_amdgcn_mfma_f32_16x16x32_fp8_fp8(
              (long)afrag[mt][kc], (long)hb, acc[mt], 0, 0, 0);
      }
    }

    // C) cell + fp8 LDS write + pack bf16 for deferred store
    {
      float hv[8];
#pragma unroll
      for (int mt = 0; mt < 8; ++mt) {
        float gi = __builtin_amdgcn_rcpf(1.0f + __builtin_exp2f(acc[mt][0] * kNI));
        float gf = __builtin_amdgcn_rcpf(1.0f + __builtin_exp2f(acc[mt][1] * kNI));
        float gg = 1.0f - 2.0f * __builtin_amdgcn_rcpf(1.0f + __builtin_exp2f(acc[mt][2] * kP2));
        float go = __builtin_amdgcn_rcpf(1.0f + __builtin_exp2f(acc[mt][3] * kNI));
        float c = gf * cst[mt] + gi * gg;
        cst[mt] = c;
        hv[mt] = go * (1.0f - 2.0f * __builtin_amdgcn_rcpf(1.0f + __builtin_exp2f(c * k2L)));
      }
      unsigned d0 = pk4_fp8(hv[0] * 16.f, hv[1] * 16.f, hv[2] * 16.f, hv[3] * 16.f);
      unsigned d1 = pk4_fp8(hv[4] * 16.f, hv[5] * 16.f, hv[6] * 16.f, hv[7] * 16.f);
      unsigned long long pk = (unsigned long long)d0 | ((unsigned long long)d1 << 32);
      *(unsigned long long*)(&h8[p ^ 1][ln15][0] + (myslot ^ swzw)) = pk;

      hpend[0] = pk_bf16(hv[0], hv[1]);
      hpend[1] = pk_bf16(hv[2], hv[3]);
      hpend[2] = pk_bf16(hv[4], hv[5]);
      hpend[3] = pk_bf16(hv[6], hv[7]);
      tpend = t;

      if (s < TSTEPS - 1) {
#pragma unroll
        for (int mt = 0; mt < 8; ++mt)
#pragma unroll
          for (int j = 0; j < 4; ++j) acc[mt][j] = b2f(xnext[mt][j]);
      }
    }

    // light barrier: drain LDS only; global ops stay in flight across it.
    asm volatile("s_waitcnt lgkmcnt(0)" ::: "memory");
    __builtin_amdgcn_s_barrier();
    __builtin_amdgcn_sched_barrier(0);
  }

  // final step's hcat store
  *(uint4v*)(hc_lane + (size_t)tpend * 16384) = hpend;
}

// ---------------- fused log-softmax + CTC loss (parallel lp precompute) ----------
#define CTC_S 17
__global__ __launch_bounds__(576) void ctc_kernel(
    const float* __restrict__ preds,   // [64][32][12]
    const int* __restrict__ text,      // [256]
    const int* __restrict__ text_len,  // [32]
    float* __restrict__ out) {
  __shared__ float lp[TSTEPS][NSEQ][12];     // 96KB normalized log-probs
  __shared__ float alpha[2][NSEQ][CTC_S];
  __shared__ int ext[NSEQ][CTC_S];
  __shared__ unsigned char allow[NSEQ][CTC_S];
  __shared__ unsigned char validm[NSEQ][CTC_S];
  __shared__ int tlsh[NSEQ];
  __shared__ float logp_sh[NSEQ];

  int tid = threadIdx.x;

  // phase 1: parallel log-softmax for all 2048 rows
  for (int r = tid; r < TSTEPS * NSEQ; r += 576) {
    const float* p = preds + (size_t)r * 12;
    float mx = p[0];
#pragma unroll
    for (int k = 1; k < 12; ++k) mx = fmaxf(mx, p[k]);
    float ssum = 0.f;
#pragma unroll
    for (int k = 0; k < 12; ++k) ssum += __expf(p[k] - mx);
    float ls = mx + __logf(ssum);
    int t = r >> 5, b = r & 31;
#pragma unroll
    for (int k = 0; k < 12; ++k) lp[t][b][k] = p[k] - ls;
  }
  if (tid < NSEQ) tlsh[tid] = text_len[tid];
  __syncthreads();

  int b = tid & 31, sIdx = tid >> 5;
  bool active = sIdx < CTC_S;

  if (active) {
    int tl = tlsh[b];
    int off = 0;
    for (int i = 0; i < b; ++i) off += tlsh[i];
    int e = 0;
    if (sIdx & 1) {
      int lbl = (sIdx - 1) >> 1;
      int idx = off + lbl;
      if (idx > 255) idx = 255;
      e = (lbl < tl) ? text[idx] : 0;
    }
    ext[b][sIdx] = e;
    validm[b][sIdx] = (sIdx < 2 * tl + 1) ? 1 : 0;
  }
  __syncthreads();
  if (active) {
    int e = ext[b][sIdx];
    bool same2 = (sIdx >= 2) && (e == ext[b][sIdx - 2]);
    allow[b][sIdx] = ((sIdx >= 2) && (e != 0) && !same2) ? 1 : 0;
    float a = -1e30f;
    if (sIdx == 0) a = lp[0][b][0];
    else if (sIdx == 1 && tlsh[b] > 0) a = lp[0][b][ext[b][1]];
    alpha[0][b][sIdx] = a;
  }
  __syncthreads();

  for (int t = 1; t < TSTEPS; ++t) {
    int cur = (t - 1) & 1, nxt = t & 1;
    if (active) {
      float a = alpha[cur][b][sIdx];
      float a1 = (sIdx >= 1) ? alpha[cur][b][sIdx - 1] : -1e30f;
      float a2 = (sIdx >= 2 && allow[b][sIdx]) ? alpha[cur][b][sIdx - 2] : -1e30f;
      float m = fmaxf(a, fmaxf(a1, a2));
      float ssum = __expf(a - m) + __expf(a1 - m) + __expf(a2 - m);
      float nv = m + __logf(ssum) + lp[t][b][ext[b][sIdx]];
      alpha[nxt][b][sIdx] = validm[b][sIdx] ? nv : -1e30f;
    }
    __syncthreads();
  }

  if (tid < NSEQ) {
    int tl = tlsh[b];
    float a1 = alpha[1][b][2 * tl];
    float a2 = (tl > 0) ? alpha[1][b][2 * tl - 1] : -1e30f;
    float m = fmaxf(a1, a2);
    logp_sh[b] = m + __logf(__expf(a1 - m) + __expf(a2 - m));
  }
  __syncthreads();
  if (tid == 0) {
    float ssum = 0.f;
    for (int i = 0; i < NSEQ; ++i) ssum += logp_sh[i];
    out[0] = -ssum / (float)NSEQ;
  }
}

// ---------------- launch ----------------
extern "C" void kernel_launch(void* const* d_in, const int* in_sizes, int n_in,
                              void* d_out, int out_size, void* d_ws, size_t ws_size,
                              hipStream_t stream) {
  (void)in_sizes; (void)n_in; (void)out_size; (void)ws_size;
  const float* base_feat = (const float*)d_in[0];
  const int* text = (const int*)d_in[1];
  const int* text_len = (const int*)d_in[2];
  const float* rois = (const float*)d_in[3];
  const float* l1_fw_W_ih = (const float*)d_in[4];
  const float* l1_fw_W_hh = (const float*)d_in[5];
  const float* l1_fw_b_ih = (const float*)d_in[6];
  const float* l1_fw_b_hh = (const float*)d_in[7];
  const float* l1_bw_W_ih = (const float*)d_in[8];
  const float* l1_bw_W_hh = (const float*)d_in[9];
  const float* l1_bw_b_ih = (const float*)d_in[10];
  const float* l1_bw_b_hh = (const float*)d_in[11];
  const float* l2_fw_W_ih = (const float*)d_in[12];
  const float* l2_fw_W_hh = (const float*)d_in[13];
  const float* l2_fw_b_ih = (const float*)d_in[14];
  const float* l2_fw_b_hh = (const float*)d_in[15];
  const float* l2_bw_W_ih = (const float*)d_in[16];
  const float* l2_bw_W_hh = (const float*)d_in[17];
  const float* l2_bw_b_ih = (const float*)d_in[18];
  const float* l2_bw_b_hh = (const float*)d_in[19];
  const float* W_emb1 = (const float*)d_in[20];
  const float* b_emb1 = (const float*)d_in[21];
  const float* W_emb2 = (const float*)d_in[22];
  const float* b_emb2 = (const float*)d_in[23];

  float* ws = (float*)d_ws;
  unsigned short* xgb  = (unsigned short*)(ws + OFF_XGB);
  unsigned short* rnnb = (unsigned short*)(ws + OFF_RNNB);
  unsigned short* w12b = (unsigned short*)(ws + OFF_W12B);
  unsigned short* w22b = (unsigned short*)(ws + OFF_W22B);
  unsigned short* we1b = (unsigned short*)(ws + OFF_WE1B);
  unsigned short* we2b = (unsigned short*)(ws + OFF_WE2B);
  float* pb1 = ws + OFF_PB1;
  float* pb2 = ws + OFF_PB2;
  unsigned char* w8l1f = (unsigned char*)(ws + OFF_W8L1F);
  unsigned char* w8l1b = (unsigned char*)(ws + OFF_W8L1B);
  unsigned char* w8l2f = (unsigned char*)(ws + OFF_W8L2F);
  unsigned char* w8l2b = (unsigned char*)(ws + OFF_W8L2B);
  unsigned short* hcb1 = (unsigned short*)(ws + OFF_HCB1);
  unsigned short* hcb2 = (unsigned short*)(ws + OFF_HCB2);
  unsigned short* h1b  = (unsigned short*)(ws + OFF_H1B);
  float* preds = ws + OFF_PREDS;

  // 0) all weight/bias prep in one launch
  prep_kernel<<<3734, 256, 0, stream>>>(
      l1_fw_W_ih, l1_bw_W_ih, l2_fw_W_ih, l2_bw_W_ih, W_emb1, W_emb2,
      l1_fw_W_hh, l1_bw_W_hh, l2_fw_W_hh, l2_bw_W_hh,
      l1_fw_b_ih, l1_fw_b_hh, l1_bw_b_ih, l1_bw_b_hh,
      l2_fw_b_ih, l2_fw_b_hh, l2_bw_b_ih, l2_bw_b_hh,
      w12b, w22b, we1b, we2b, w8l1f, w8l1b, w8l2f, w8l2b, pb1, pb2);

  // 1) ROI max pool -> rnn bf16 [2048][1024]
  roi_pool_kernel<<<dim3(32, 256), 256, 0, stream>>>(base_feat, rois, rnnb);

  // 2) xg layer1, both dirs in one launch (mode 5)
  gemm_bf16<<<dim3(16, 16), 256, 0, stream>>>(w12b, rnnb, nullptr, xgb,
      2048, 2048, 1024, pb1, nullptr, 5);

  // 3) layer-1 recurrence
  lstm_layer10<<<4, 512, 0, stream>>>(xgb, w8l1f, w8l1b, hcb1);

  // 4) h1 = hcat1 @ W_emb1^T + b_emb1 -> bf16 [2048][256] (pi-cols cancel)
  gemm_bf16<<<dim3(2, 16), 256, 0, stream>>>(hcb1, we1b, nullptr, h1b,
      2048, 256, 512, nullptr, b_emb1, 1);

  // 5) xg layer2 (mode 5)
  gemm_bf16<<<dim3(16, 16), 256, 0, stream>>>(w22b, h1b, nullptr, xgb,
      2048, 2048, 256, pb2, nullptr, 5);

  // 6) layer-2 recurrence
  lstm_layer10<<<4, 512, 0, stream>>>(xgb, w8l2f, w8l2b, hcb2);

  // 7) preds = hcat2 @ W_emb2^T + b_emb2 (f32, N=12 guarded, pi-cols cancel)
  gemm_bf16<<<dim3(1, 16), 256, 0, stream>>>(hcb2, we2b, preds, nullptr,
      2048, 12, 512, nullptr, b_emb2, 0);

  // 8) log-softmax + CTC
  ctc_kernel<<<1, 576, 0, stream>>>(preds, text, text_len, (float*)d_out);
}

// Round 12
// 507.520 us; speedup vs baseline: 1.0369x; 1.0369x over previous
//
#include <hip/hip_runtime.h>
#include <math.h>

// ---------------- problem constants ----------------
#define TSTEPS 64
#define NSEQ   32
#define FH     40
#define FW     160

// ---------------- workspace layout (float units) ----------------
#define OFF_XGB    0u            // [2][64 t][256 unit][32 n][4 gate] bf16, x1024
#define OFF_RNNB   2097152u      // [2048 tn][1024] bf16
#define OFF_W12B   3145728u      // W_ih l1 bf16, row-permuted unit*4+gate, [2048][1024]
#define OFF_W22B   4194304u      // W_ih l2 bf16 permuted [2048][256]
#define OFF_WE1B   4456448u      // W_emb1 bf16 [256][512], COLUMNS pi-permuted
#define OFF_WE2B   4521984u      // W_emb2 bf16 [12][512], COLUMNS pi-permuted
#define OFF_PB1    4525056u      // combined permuted bias l1 [2048] f32
#define OFF_PB2    4527104u      // combined permuted bias l2 [2048] f32
#define OFF_W8L1F  4529152u      // W_hh fp8 (x64) k-permuted [1024][256]
#define OFF_W8L1B  4594688u
#define OFF_W8L2F  4660224u
#define OFF_W8L2B  4725760u
#define OFF_HCB1   4791296u      // hcat1 bf16 [2048][512] (pi-permuted cols)
#define OFF_HCB2   5315584u
#define OFF_H1B    5839872u      // h1 bf16 [2048][256]
#define OFF_PREDS  6102016u      // [2048][12] f32

typedef __attribute__((ext_vector_type(8))) short short8;
typedef __attribute__((ext_vector_type(4))) float f32x4;
typedef __attribute__((ext_vector_type(4))) unsigned short ushort4v;
typedef __attribute__((ext_vector_type(4))) unsigned uint4v;

static __device__ inline unsigned short bf16c(float x) {
  union { float f; unsigned u; } v; v.f = x;
  unsigned r = v.u + 0x7fff + ((v.u >> 16) & 1);   // RNE
  return (unsigned short)(r >> 16);
}
static __device__ inline float b2f(unsigned short u) {
  union { unsigned u; float f; } v; v.u = ((unsigned)u) << 16;
  return v.f;
}
// pack 2 f32 -> u32 of 2 bf16 (hardware cvt_pk, RNE)
static __device__ inline unsigned pk_bf16(float lo, float hi) {
  unsigned r;
  asm("v_cvt_pk_bf16_f32 %0, %1, %2" : "=v"(r) : "v"(lo), "v"(hi));
  return r;
}
// f32 -> fp8 e4m3fn (OCP): RNE, saturate, flush subnormals
static __device__ inline unsigned char fp8c(float x) {
  union { float f; unsigned u; } v; v.f = x;
  unsigned s = (v.u >> 24) & 0x80;
  float ax = fabsf(x);
  if (ax < 0.015625f) return (unsigned char)s;
  if (ax >= 448.0f) return (unsigned char)(s | 0x7e);
  unsigned e = (v.u >> 23) & 0xff;
  unsigned m = v.u & 0x7fffff;
  unsigned r = m + 0x7ffff + ((m >> 20) & 1);
  if (r >> 23) { e += 1; r = 0; }
  unsigned m3 = (r >> 20) & 7;
  int ee = (int)e - 127 + 7;
  if (ee > 15) return (unsigned char)(s | 0x7e);
  return (unsigned char)(s | (ee << 3) | m3);
}
static __device__ inline unsigned pk4_fp8(float a, float b, float c, float d) {
#if __has_builtin(__builtin_amdgcn_cvt_pk_fp8_f32)
  int r = __builtin_amdgcn_cvt_pk_fp8_f32(a, b, 0, false);
  r = __builtin_amdgcn_cvt_pk_fp8_f32(c, d, r, true);
  return (unsigned)r;
#else
  return (unsigned)fp8c(a) | ((unsigned)fp8c(b) << 8)
       | ((unsigned)fp8c(c) << 16) | ((unsigned)fp8c(d) << 24);
#endif
}

// ---------------- single prep kernel (now also does ROI max pool) ----------------
// blocks: [0,2048) l1 W_ih bf16 perm | [2048,2560) l2 W_ih | [2560,2688) we1 pi-col |
// [2688,2694) we2 pi-col | [2694,3718) fp8 W_hh x4 | [3718,3726) pb1 | [3726,3734) pb2
// | [3734,11926) roi pool: b2 = b-3734, n = b2>>8, cg = b2&255
__global__ __launch_bounds__(256) void prep_kernel(
    const float* __restrict__ w1f, const float* __restrict__ w1b,
    const float* __restrict__ w2f, const float* __restrict__ w2b,
    const float* __restrict__ we1, const float* __restrict__ we2,
    const float* __restrict__ wh1f, const float* __restrict__ wh1b,
    const float* __restrict__ wh2f, const float* __restrict__ wh2b,
    const float* __restrict__ b1fi, const float* __restrict__ b1fh,
    const float* __restrict__ b1bi, const float* __restrict__ b1bh,
    const float* __restrict__ b2fi, const float* __restrict__ b2fh,
    const float* __restrict__ b2bi, const float* __restrict__ b2bh,
    const float* __restrict__ feat, const float* __restrict__ rois,
    unsigned short* __restrict__ w12b, unsigned short* __restrict__ w22b,
    unsigned short* __restrict__ we1o, unsigned short* __restrict__ we2o,
    unsigned char* __restrict__ o8l1f, unsigned char* __restrict__ o8l1b,
    unsigned char* __restrict__ o8l2f, unsigned char* __restrict__ o8l2b,
    float* __restrict__ pb1, float* __restrict__ pb2,
    unsigned short* __restrict__ rnn) {
  int b = blockIdx.x, tid = threadIdx.x;
  if (b < 2048) {
    const float* src = (b < 1024) ? w1f : w1b;
    unsigned short* dst = w12b + (size_t)((b < 1024) ? 0 : 1048576);
    int i = (b & 1023) * 256 + tid;
    int row = i >> 8, c4 = i & 255;
    int orow = (row & 255) * 4 + (row >> 8);   // gate*256+unit -> unit*4+gate
    float4 v = ((const float4*)src)[i];
    ushort4v o; o[0]=bf16c(v.x); o[1]=bf16c(v.y); o[2]=bf16c(v.z); o[3]=bf16c(v.w);
    *(ushort4v*)(dst + (size_t)orow * 1024 + c4 * 4) = o;
  } else if (b < 2560) {
    int bb = b - 2048;
    const float* src = (bb < 256) ? w2f : w2b;
    unsigned short* dst = w22b + (size_t)((bb < 256) ? 0 : 262144);
    int i = (bb & 255) * 256 + tid;
    int row = i >> 6, c4 = i & 63;
    int orow = (row & 255) * 4 + (row >> 8);
    float4 v = ((const float4*)src)[i];
    ushort4v o; o[0]=bf16c(v.x); o[1]=bf16c(v.y); o[2]=bf16c(v.z); o[3]=bf16c(v.w);
    *(ushort4v*)(dst + (size_t)orow * 256 + c4 * 4) = o;
  } else if (b < 2688) {
    // we1: out[j][d*256 + k] = in[j][d*256 + invpi(k)], invpi(k) = (k>>6) + (k&63)*4
    int i = (b - 2560) * 256 + tid;
    int j = i >> 7, c4 = (i & 127) * 4;
    ushort4v o;
#pragma unroll
    for (int q = 0; q < 4; ++q) {
      int c = c4 + q;
      int d = c >> 8, k = c & 255;
      int u = (k >> 6) + (k & 63) * 4;
      o[q] = bf16c(we1[(size_t)j * 512 + d * 256 + u]);
    }
    ((ushort4v*)we1o)[i] = o;
  } else if (b < 2694) {
    int i = (b - 2688) * 256 + tid;
    int j = i >> 7, c4 = (i & 127) * 4;
    ushort4v o;
#pragma unroll
    for (int q = 0; q < 4; ++q) {
      int c = c4 + q;
      int d = c >> 8, k = c & 255;
      int u = (k >> 6) + (k & 63) * 4;
      o[q] = bf16c(we2[(size_t)j * 512 + d * 256 + u]);
    }
    ((ushort4v*)we2o)[i] = o;
  } else if (b < 3718) {
    int bb = b - 2694;
    int which = bb >> 8;
    const float* src = (which == 0) ? wh1f : (which == 1) ? wh1b
                     : (which == 2) ? wh2f : wh2b;
    unsigned char* dst = (which == 0) ? o8l1f : (which == 1) ? o8l1b
                       : (which == 2) ? o8l2f : o8l2b;
    int idx = (bb & 255) * 256 + tid;
    int row = idx >> 6, k4 = (idx & 63) * 4;
    const float* r = src + (size_t)row * 256;
    unsigned o = 0;
#pragma unroll
    for (int j = 0; j < 4; ++j) {
      int kp = k4 + j;
      int u = (kp >> 6) + (kp & 63) * 4;       // inverse k-permute
      o |= ((unsigned)fp8c(r[u] * 64.0f)) << (8 * j);
    }
    ((unsigned*)dst)[idx] = o;
  } else if (b < 3726) {
    int m = (b - 3718) * 256 + tid;
    int dirq = m >> 10, mloc = m & 1023;
    int r = (mloc & 3) * 256 + (mloc >> 2);
    pb1[m] = dirq ? (b1bi[r] + b1bh[r]) : (b1fi[r] + b1fh[r]);
  } else if (b < 3734) {
    int m = (b - 3726) * 256 + tid;
    int dirq = m >> 10, mloc = m & 1023;
    int r = (mloc & 3) * 256 + (mloc >> 2);
    pb2[m] = dirq ? (b2bi[r] + b2bh[r]) : (b2fi[r] + b2fh[r]);
  } else {
    // ROI max pool
    int b2 = b - 3734;
    int n = b2 >> 8, cg = b2 & 255;
    int pw = tid & 63, ph = (tid >> 6) & 1, cl = tid >> 7;
    int c = cg * 2 + cl;

    const float* r = rois + n * 5;
    int bi = (int)r[0];
    int x1 = (int)rintf(r[1] * (float)FW);
    int y1 = (int)rintf(r[2] * (float)FH);
    int x2 = (int)rintf(r[3] * (float)FW);
    int y2 = (int)rintf(r[4] * (float)FH);
    float rw = fmaxf((float)(x2 - x1 + 1), 1.0f);
    float rh = fmaxf((float)(y2 - y1 + 1), 1.0f);
    float bin_h = rh * 0.5f;
    float bin_w = rw * (1.0f / 64.0f);

    int hs = min(max((int)floorf((float)ph * bin_h) + y1, 0), FH);
    int he = min(max((int)ceilf((float)(ph + 1) * bin_h) + y1, 0), FH);
    int wst = min(max((int)floorf((float)pw * bin_w) + x1, 0), FW);
    int wen = min(max((int)ceilf((float)(pw + 1) * bin_w) + x1, 0), FW);

    float m = -1e30f;
    bool nonempty = (hs < he) && (wst < wen);
    const float* f = feat + ((size_t)bi * 512 + c) * (FH * FW);
    for (int h = hs; h < he; ++h) {
      const float* fr = f + h * FW;
      for (int w = wst; w < wen; ++w) m = fmaxf(m, fr[w]);
    }
    float out = nonempty ? m : 0.0f;
    rnn[((size_t)pw * NSEQ + n) * 1024 + c * 2 + ph] = bf16c(out);
  }
}

// ---------------- bf16 MFMA GEMM ----------------
// mode 0: Cf[m*N+n] f32; mode 1: Cb[m*N+n] bf16;
// mode 5: xg write: Cb[dir*2097152 + ((t*256+unit)*32+n)*4 + gate] = bf16(v*1024)
#define GPITCH 40
__global__ __launch_bounds__(256) void gemm_bf16(
    const unsigned short* __restrict__ A, const unsigned short* __restrict__ B,
    float* __restrict__ Cf, unsigned short* __restrict__ Cb,
    int M, int N, int K,
    const float* __restrict__ bm1, const float* __restrict__ bn, int mode) {
  __shared__ unsigned short Al[128 * GPITCH];
  __shared__ unsigned short Bl[128 * GPITCH];
  int m0 = blockIdx.y * 128, n0 = blockIdx.x * 128;
  int tid = threadIdx.x;
  int wid = tid >> 6, l = tid & 63, ln15 = l & 15, kg = l >> 4;
  int wm = wid >> 1, wn = wid & 1;

  f32x4 acc[4][4];
#pragma unroll
  for (int i = 0; i < 4; ++i)
#pragma unroll
    for (int j = 0; j < 4; ++j)
#pragma unroll
      for (int q = 0; q < 4; ++q) acc[i][j][q] = 0.0f;

  for (int k0 = 0; k0 < K; k0 += 32) {
#pragma unroll
    for (int it = 0; it < 2; ++it) {
      int chunk = tid + it * 256;
      int row = chunk >> 2, part = chunk & 3;
      short8 va = *(const short8*)(A + (size_t)(m0 + row) * K + k0 + part * 8);
      *(short8*)(Al + row * GPITCH + part * 8) = va;
      short8 vb;
      if (n0 + row < N) {
        vb = *(const short8*)(B + (size_t)(n0 + row) * K + k0 + part * 8);
      } else {
#pragma unroll
        for (int q = 0; q < 8; ++q) vb[q] = 0;
      }
      *(short8*)(Bl + row * GPITCH + part * 8) = vb;
    }
    __syncthreads();

    short8 a[4], b[4];
#pragma unroll
    for (int mt = 0; mt < 4; ++mt)
      a[mt] = *(const short8*)(Al + (wm * 64 + mt * 16 + ln15) * GPITCH + kg * 8);
#pragma unroll
    for (int nt = 0; nt < 4; ++nt)
      b[nt] = *(const short8*)(Bl + (wn * 64 + nt * 16 + ln15) * GPITCH + kg * 8);
#pragma unroll
    for (int mt = 0; mt < 4; ++mt)
#pragma unroll
      for (int nt = 0; nt < 4; ++nt)
        acc[mt][nt] = __builtin_amdgcn_mfma_f32_16x16x32_bf16(a[mt], b[nt], acc[mt][nt], 0, 0, 0);
    __syncthreads();
  }

  if (mode == 5) {
#pragma unroll
    for (int mt = 0; mt < 4; ++mt) {
      int mbase = m0 + wm * 64 + mt * 16 + kg * 4;
      f32x4 pbv = *(const f32x4*)(bm1 + mbase);
      int dirq = mbase >> 10;
      int unit = (mbase & 1023) >> 2;
#pragma unroll
      for (int nt = 0; nt < 4; ++nt) {
        int col = n0 + wn * 64 + nt * 16 + ln15;
        int t = col >> 5, n = col & 31;
        ushort4v q;
#pragma unroll
        for (int j = 0; j < 4; ++j)
          q[j] = bf16c((acc[mt][nt][j] + pbv[j]) * 1024.0f);
        *(ushort4v*)(Cb + (size_t)dirq * 2097152u + ((t << 8) + unit) * 128 + n * 4) = q;
      }
    }
    return;
  }

#pragma unroll
  for (int mt = 0; mt < 4; ++mt) {
#pragma unroll
    for (int j = 0; j < 4; ++j) {
      int m = m0 + wm * 64 + mt * 16 + kg * 4 + j;
      float bmv = bm1 ? bm1[m] : 0.0f;
#pragma unroll
      for (int nt = 0; nt < 4; ++nt) {
        int n = n0 + wn * 64 + nt * 16 + ln15;
        if (n < N) {
          float v = acc[mt][nt][j] + bmv;
          if (bn) v += bn[n];
          if (mode == 1) Cb[(size_t)m * N + n] = bf16c(v);
          else Cf[(size_t)m * N + n] = v;
        }
      }
    }
  }
}

// ---------------- persistent BiLSTM layer v11: R9 base + deferred store + exp2 ---
// Grid 4 blocks: dir = blk>>1, batch-half = blk&1 (16 n). 512 thr = 8 waves,
// 8 mt/wave. Standard __syncthreads (no light barrier, no sched_barrier).
// hcat store deferred to top of next iteration; exp2 with folded log2e.
__global__ __launch_bounds__(512, 2) void lstm_layer11(
    const unsigned short* __restrict__ xgb,  // [dir][t][unit][n][gate] bf16, x1024
    const unsigned char* __restrict__ w8fw,  // [1024][256] fp8 (x64), k-permuted
    const unsigned char* __restrict__ w8bw,
    unsigned short* __restrict__ hcatb) {    // [64][32][512] bf16, pi-cols
  const int dir = blockIdx.x >> 1;
  const int nbase = (blockIdx.x & 1) * 16;
  const int tid = threadIdx.x;
  const int w = tid >> 6;
  const int l = tid & 63;
  const int ln15 = l & 15;
  const int kg = l >> 4;
  const int u_wave = w * 32;

  __shared__ unsigned char h8[2][16][256];   // fp8 h (x16), k-permuted + swizzled

  const unsigned char* W8 = dir ? w8bw : w8fw;

  unsigned long long afrag[8][8];
  {
    int gate = ln15 & 3, du = ln15 >> 2;
#pragma unroll
    for (int mt = 0; mt < 8; ++mt) {
      const unsigned char* wr = W8 + (size_t)((gate << 8) + u_wave + mt * 4 + du) * 256;
#pragma unroll
      for (int kc = 0; kc < 8; ++kc)
        afrag[mt][kc] = *(const unsigned long long*)(wr + kc * 32 + kg * 8);
    }
  }

  const unsigned short* xgd = xgb + (size_t)dir * 2097152u;
  const int lane_off = (nbase + ln15) * 4;
  float cst[8] = {0.f, 0.f, 0.f, 0.f, 0.f, 0.f, 0.f, 0.f};
  f32x4 acc[8];
  ushort4v xnext[8];
  uint4v hpend;                      // previous step's 8 h as bf16 (deferred store)
  int tpend = 0;

  {
    int t0 = dir ? 63 : 0;
    const unsigned short* xb = xgd + (size_t)t0 * 32768 + lane_off;
#pragma unroll
    for (int mt = 0; mt < 8; ++mt)
      xnext[mt] = *(const ushort4v*)(xb + (u_wave + mt * 4 + kg) * 128);
#pragma unroll
    for (int mt = 0; mt < 8; ++mt)
#pragma unroll
      for (int j = 0; j < 4; ++j) acc[mt][j] = b2f(xnext[mt][j]);
  }

  const int swzw = (ln15 & 7) << 4;
  const int myslot = kg * 64 + w * 8;        // pi-slot of this lane's 8 h (contig mt)
  unsigned short* hc_lane = hcatb + (size_t)(nbase + ln15) * 512 + dir * 256 + myslot;
  const float kNI = -1.442695041f / 1024.0f;  // -log2e/1024
  const float kP2 = 2.885390082f / 1024.0f;   // +2*log2e/1024
  const float k2L = 2.885390082f;             // 2*log2e

  for (int s = 0; s < TSTEPS; ++s) {
    const int t = dir ? (63 - s) : s;
    const int p = s & 1;

    // A0) deferred hcat store of previous step's h (drains during MFMA+cell)
    if (s > 0)
      *(uint4v*)(hc_lane + (size_t)tpend * 16384) = hpend;

    // A) issue next-step xg loads
    if (s < TSTEPS - 1) {
      int tn2 = dir ? (t - 1) : (t + 1);
      const unsigned short* xb = xgd + (size_t)tn2 * 32768 + lane_off;
#pragma unroll
      for (int mt = 0; mt < 8; ++mt)
        xnext[mt] = *(const ushort4v*)(xb + (u_wave + mt * 4 + kg) * 128);
    }

    // B) MFMA: acc += (64*W)(16*h)
    if (s > 0) {
      const unsigned char* hrow = &h8[p][ln15][0];
#pragma unroll
      for (int kc = 0; kc < 8; ++kc) {
        unsigned long long hb =
            *(const unsigned long long*)(hrow + ((kc * 32 + kg * 8) ^ swzw));
#pragma unroll
        for (int mt = 0; mt < 8; ++mt)
          acc[mt] = __builtin_amdgcn_mfma_f32_16x16x32_fp8_fp8(
              (long)afrag[mt][kc], (long)hb, acc[mt], 0, 0, 0);
      }
    }

    // C) cell + fp8 LDS write + pack bf16 for deferred store
    {
      float hv[8];
#pragma unroll
      for (int mt = 0; mt < 8; ++mt) {
        float gi = __builtin_amdgcn_rcpf(1.0f + __builtin_exp2f(acc[mt][0] * kNI));
        float gf = __builtin_amdgcn_rcpf(1.0f + __builtin_exp2f(acc[mt][1] * kNI));
        float gg = 1.0f - 2.0f * __builtin_amdgcn_rcpf(1.0f + __builtin_exp2f(acc[mt][2] * kP2));
        float go = __builtin_amdgcn_rcpf(1.0f + __builtin_exp2f(acc[mt][3] * kNI));
        float c = gf * cst[mt] + gi * gg;
        cst[mt] = c;
        hv[mt] = go * (1.0f - 2.0f * __builtin_amdgcn_rcpf(1.0f + __builtin_exp2f(c * k2L)));
      }
      unsigned d0 = pk4_fp8(hv[0] * 16.f, hv[1] * 16.f, hv[2] * 16.f, hv[3] * 16.f);
      unsigned d1 = pk4_fp8(hv[4] * 16.f, hv[5] * 16.f, hv[6] * 16.f, hv[7] * 16.f);
      unsigned long long pk = (unsigned long long)d0 | ((unsigned long long)d1 << 32);
      *(unsigned long long*)(&h8[p ^ 1][ln15][0] + (myslot ^ swzw)) = pk;

      hpend[0] = pk_bf16(hv[0], hv[1]);
      hpend[1] = pk_bf16(hv[2], hv[3]);
      hpend[2] = pk_bf16(hv[4], hv[5]);
      hpend[3] = pk_bf16(hv[6], hv[7]);
      tpend = t;

      if (s < TSTEPS - 1) {
#pragma unroll
        for (int mt = 0; mt < 8; ++mt)
#pragma unroll
          for (int j = 0; j < 4; ++j) acc[mt][j] = b2f(xnext[mt][j]);
      }
    }

    __syncthreads();
  }

  // final step's hcat store
  *(uint4v*)(hc_lane + (size_t)tpend * 16384) = hpend;
}

// ---------------- fused log-softmax + CTC loss (parallel lp precompute) ----------
#define CTC_S 17
__global__ __launch_bounds__(576) void ctc_kernel(
    const float* __restrict__ preds,   // [64][32][12]
    const int* __restrict__ text,      // [256]
    const int* __restrict__ text_len,  // [32]
    float* __restrict__ out) {
  __shared__ float lp[TSTEPS][NSEQ][12];     // 96KB normalized log-probs
  __shared__ float alpha[2][NSEQ][CTC_S];
  __shared__ int ext[NSEQ][CTC_S];
  __shared__ unsigned char allow[NSEQ][CTC_S];
  __shared__ unsigned char validm[NSEQ][CTC_S];
  __shared__ int tlsh[NSEQ];
  __shared__ float logp_sh[NSEQ];

  int tid = threadIdx.x;

  // phase 1: parallel log-softmax for all 2048 rows
  for (int r = tid; r < TSTEPS * NSEQ; r += 576) {
    const float* p = preds + (size_t)r * 12;
    float mx = p[0];
#pragma unroll
    for (int k = 1; k < 12; ++k) mx = fmaxf(mx, p[k]);
    float ssum = 0.f;
#pragma unroll
    for (int k = 0; k < 12; ++k) ssum += __expf(p[k] - mx);
    float ls = mx + __logf(ssum);
    int t = r >> 5, b = r & 31;
#pragma unroll
    for (int k = 0; k < 12; ++k) lp[t][b][k] = p[k] - ls;
  }
  if (tid < NSEQ) tlsh[tid] = text_len[tid];
  __syncthreads();

  int b = tid & 31, sIdx = tid >> 5;
  bool active = sIdx < CTC_S;

  if (active) {
    int tl = tlsh[b];
    int off = 0;
    for (int i = 0; i < b; ++i) off += tlsh[i];
    int e = 0;
    if (sIdx & 1) {
      int lbl = (sIdx - 1) >> 1;
      int idx = off + lbl;
      if (idx > 255) idx = 255;
      e = (lbl < tl) ? text[idx] : 0;
    }
    ext[b][sIdx] = e;
    validm[b][sIdx] = (sIdx < 2 * tl + 1) ? 1 : 0;
  }
  __syncthreads();
  if (active) {
    int e = ext[b][sIdx];
    bool same2 = (sIdx >= 2) && (e == ext[b][sIdx - 2]);
    allow[b][sIdx] = ((sIdx >= 2) && (e != 0) && !same2) ? 1 : 0;
    float a = -1e30f;
    if (sIdx == 0) a = lp[0][b][0];
    else if (sIdx == 1 && tlsh[b] > 0) a = lp[0][b][ext[b][1]];
    alpha[0][b][sIdx] = a;
  }
  __syncthreads();

  for (int t = 1; t < TSTEPS; ++t) {
    int cur = (t - 1) & 1, nxt = t & 1;
    if (active) {
      float a = alpha[cur][b][sIdx];
      float a1 = (sIdx >= 1) ? alpha[cur][b][sIdx - 1] : -1e30f;
      float a2 = (sIdx >= 2 && allow[b][sIdx]) ? alpha[cur][b][sIdx - 2] : -1e30f;
      float m = fmaxf(a, fmaxf(a1, a2));
      float ssum = __expf(a - m) + __expf(a1 - m) + __expf(a2 - m);
      float nv = m + __logf(ssum) + lp[t][b][ext[b][sIdx]];
      alpha[nxt][b][sIdx] = validm[b][sIdx] ? nv : -1e30f;
    }
    __syncthreads();
  }

  if (tid < NSEQ) {
    int tl = tlsh[b];
    float a1 = alpha[1][b][2 * tl];
    float a2 = (tl > 0) ? alpha[1][b][2 * tl - 1] : -1e30f;
    float m = fmaxf(a1, a2);
    logp_sh[b] = m + __logf(__expf(a1 - m) + __expf(a2 - m));
  }
  __syncthreads();
  if (tid == 0) {
    float ssum = 0.f;
    for (int i = 0; i < NSEQ; ++i) ssum += logp_sh[i];
    out[0] = -ssum / (float)NSEQ;
  }
}

// ---------------- launch ----------------
extern "C" void kernel_launch(void* const* d_in, const int* in_sizes, int n_in,
                              void* d_out, int out_size, void* d_ws, size_t ws_size,
                              hipStream_t stream) {
  (void)in_sizes; (void)n_in; (void)out_size; (void)ws_size;
  const float* base_feat = (const float*)d_in[0];
  const int* text = (const int*)d_in[1];
  const int* text_len = (const int*)d_in[2];
  const float* rois = (const float*)d_in[3];
  const float* l1_fw_W_ih = (const float*)d_in[4];
  const float* l1_fw_W_hh = (const float*)d_in[5];
  const float* l1_fw_b_ih = (const float*)d_in[6];
  const float* l1_fw_b_hh = (const float*)d_in[7];
  const float* l1_bw_W_ih = (const float*)d_in[8];
  const float* l1_bw_W_hh = (const float*)d_in[9];
  const float* l1_bw_b_ih = (const float*)d_in[10];
  const float* l1_bw_b_hh = (const float*)d_in[11];
  const float* l2_fw_W_ih = (const float*)d_in[12];
  const float* l2_fw_W_hh = (const float*)d_in[13];
  const float* l2_fw_b_ih = (const float*)d_in[14];
  const float* l2_fw_b_hh = (const float*)d_in[15];
  const float* l2_bw_W_ih = (const float*)d_in[16];
  const float* l2_bw_W_hh = (const float*)d_in[17];
  const float* l2_bw_b_ih = (const float*)d_in[18];
  const float* l2_bw_b_hh = (const float*)d_in[19];
  const float* W_emb1 = (const float*)d_in[20];
  const float* b_emb1 = (const float*)d_in[21];
  const float* W_emb2 = (const float*)d_in[22];
  const float* b_emb2 = (const float*)d_in[23];

  float* ws = (float*)d_ws;
  unsigned short* xgb  = (unsigned short*)(ws + OFF_XGB);
  unsigned short* rnnb = (unsigned short*)(ws + OFF_RNNB);
  unsigned short* w12b = (unsigned short*)(ws + OFF_W12B);
  unsigned short* w22b = (unsigned short*)(ws + OFF_W22B);
  unsigned short* we1b = (unsigned short*)(ws + OFF_WE1B);
  unsigned short* we2b = (unsigned short*)(ws + OFF_WE2B);
  float* pb1 = ws + OFF_PB1;
  float* pb2 = ws + OFF_PB2;
  unsigned char* w8l1f = (unsigned char*)(ws + OFF_W8L1F);
  unsigned char* w8l1b = (unsigned char*)(ws + OFF_W8L1B);
  unsigned char* w8l2f = (unsigned char*)(ws + OFF_W8L2F);
  unsigned char* w8l2b = (unsigned char*)(ws + OFF_W8L2B);
  unsigned short* hcb1 = (unsigned short*)(ws + OFF_HCB1);
  unsigned short* hcb2 = (unsigned short*)(ws + OFF_HCB2);
  unsigned short* h1b  = (unsigned short*)(ws + OFF_H1B);
  float* preds = ws + OFF_PREDS;

  // 0) all weight/bias prep + ROI pool in one launch
  prep_kernel<<<11926, 256, 0, stream>>>(
      l1_fw_W_ih, l1_bw_W_ih, l2_fw_W_ih, l2_bw_W_ih, W_emb1, W_emb2,
      l1_fw_W_hh, l1_bw_W_hh, l2_fw_W_hh, l2_bw_W_hh,
      l1_fw_b_ih, l1_fw_b_hh, l1_bw_b_ih, l1_bw_b_hh,
      l2_fw_b_ih, l2_fw_b_hh, l2_bw_b_ih, l2_bw_b_hh,
      base_feat, rois,
      w12b, w22b, we1b, we2b, w8l1f, w8l1b, w8l2f, w8l2b, pb1, pb2, rnnb);

  // 1) xg layer1, both dirs in one launch (mode 5)
  gemm_bf16<<<dim3(16, 16), 256, 0, stream>>>(w12b, rnnb, nullptr, xgb,
      2048, 2048, 1024, pb1, nullptr, 5);

  // 2) layer-1 recurrence
  lstm_layer11<<<4, 512, 0, stream>>>(xgb, w8l1f, w8l1b, hcb1);

  // 3) h1 = hcat1 @ W_emb1^T + b_emb1 -> bf16 [2048][256] (pi-cols cancel)
  gemm_bf16<<<dim3(2, 16), 256, 0, stream>>>(hcb1, we1b, nullptr, h1b,
      2048, 256, 512, nullptr, b_emb1, 1);

  // 4) xg layer2 (mode 5)
  gemm_bf16<<<dim3(16, 16), 256, 0, stream>>>(w22b, h1b, nullptr, xgb,
      2048, 2048, 256, pb2, nullptr, 5);

  // 5) layer-2 recurrence
  lstm_layer11<<<4, 512, 0, stream>>>(xgb, w8l2f, w8l2b, hcb2);

  // 6) preds = hcat2 @ W_emb2^T + b_emb2 (f32, N=12 guarded, pi-cols cancel)
  gemm_bf16<<<dim3(1, 16), 256, 0, stream>>>(hcb2, we2b, preds, nullptr,
      2048, 12, 512, nullptr, b_emb2, 0);

  // 7) log-softmax + CTC
  ctc_kernel<<<1, 576, 0, stream>>>(preds, text, text_len, (float*)d_out);
}

// Round 13
// 446.495 us; speedup vs baseline: 1.1787x; 1.1367x over previous
//
#include <hip/hip_runtime.h>
#include <math.h>

// ---------------- problem constants ----------------
#define TSTEPS 64
#define NSEQ   32
#define FH     40
#define FW     160

// ---------------- workspace layout (float units) ----------------
#define OFF_XGB    0u            // [2][64 t][256 unit][32 n][4 gate] bf16, x1024
#define OFF_RNNB   2097152u      // [2048 tn][1024] bf16
#define OFF_W12B   3145728u      // W_ih l1 bf16, row-permuted unit*4+gate, [2048][1024]
#define OFF_W22B   4194304u      // W_ih l2 bf16 permuted [2048][256]
#define OFF_WE1B   4456448u      // W_emb1 bf16 [256][512], COLUMNS pi-permuted
#define OFF_WE2B   4521984u      // W_emb2 bf16 [12][512], COLUMNS pi-permuted
#define OFF_PB1    4525056u      // combined permuted bias l1 [2048] f32
#define OFF_PB2    4527104u      // combined permuted bias l2 [2048] f32
#define OFF_W8L1F  4529152u      // W_hh fp8 (x64) k-permuted [1024][256]
#define OFF_W8L1B  4594688u
#define OFF_W8L2F  4660224u
#define OFF_W8L2B  4725760u
#define OFF_HCB1   4791296u      // hcat1 bf16 [2048][512] (pi-permuted cols)
#define OFF_HCB2   5315584u
#define OFF_H1B    5839872u      // h1 bf16 [2048][256]
#define OFF_PREDS  6102016u      // [2048][12] f32

typedef __attribute__((ext_vector_type(8))) short short8;
typedef __attribute__((ext_vector_type(4))) float f32x4;
typedef __attribute__((ext_vector_type(4))) unsigned short ushort4v;
typedef __attribute__((ext_vector_type(4))) unsigned uint4v;

static __device__ inline unsigned short bf16c(float x) {
  union { float f; unsigned u; } v; v.f = x;
  unsigned r = v.u + 0x7fff + ((v.u >> 16) & 1);   // RNE
  return (unsigned short)(r >> 16);
}
static __device__ inline float b2f(unsigned short u) {
  union { unsigned u; float f; } v; v.u = ((unsigned)u) << 16;
  return v.f;
}
// pack 2 f32 -> u32 of 2 bf16 (hardware cvt_pk, RNE)
static __device__ inline unsigned pk_bf16(float lo, float hi) {
  unsigned r;
  asm("v_cvt_pk_bf16_f32 %0, %1, %2" : "=v"(r) : "v"(lo), "v"(hi));
  return r;
}
// f32 -> fp8 e4m3fn (OCP): RNE, saturate, flush subnormals
static __device__ inline unsigned char fp8c(float x) {
  union { float f; unsigned u; } v; v.f = x;
  unsigned s = (v.u >> 24) & 0x80;
  float ax = fabsf(x);
  if (ax < 0.015625f) return (unsigned char)s;
  if (ax >= 448.0f) return (unsigned char)(s | 0x7e);
  unsigned e = (v.u >> 23) & 0xff;
  unsigned m = v.u & 0x7fffff;
  unsigned r = m + 0x7ffff + ((m >> 20) & 1);
  if (r >> 23) { e += 1; r = 0; }
  unsigned m3 = (r >> 20) & 7;
  int ee = (int)e - 127 + 7;
  if (ee > 15) return (unsigned char)(s | 0x7e);
  return (unsigned char)(s | (ee << 3) | m3);
}
static __device__ inline unsigned pk4_fp8(float a, float b, float c, float d) {
#if __has_builtin(__builtin_amdgcn_cvt_pk_fp8_f32)
  int r = __builtin_amdgcn_cvt_pk_fp8_f32(a, b, 0, false);
  r = __builtin_amdgcn_cvt_pk_fp8_f32(c, d, r, true);
  return (unsigned)r;
#else
  return (unsigned)fp8c(a) | ((unsigned)fp8c(b) << 8)
       | ((unsigned)fp8c(c) << 16) | ((unsigned)fp8c(d) << 24);
#endif
}

// ---------------- single prep kernel (weights/biases + ROI max pool) ----------------
// blocks: [0,2048) l1 W_ih bf16 perm | [2048,2560) l2 W_ih | [2560,2688) we1 pi-col |
// [2688,2694) we2 pi-col | [2694,3718) fp8 W_hh x4 | [3718,3726) pb1 | [3726,3734) pb2
// | [3734,11926) roi pool: b2 = b-3734, n = b2>>8, cg = b2&255
__global__ __launch_bounds__(256) void prep_kernel(
    const float* __restrict__ w1f, const float* __restrict__ w1b,
    const float* __restrict__ w2f, const float* __restrict__ w2b,
    const float* __restrict__ we1, const float* __restrict__ we2,
    const float* __restrict__ wh1f, const float* __restrict__ wh1b,
    const float* __restrict__ wh2f, const float* __restrict__ wh2b,
    const float* __restrict__ b1fi, const float* __restrict__ b1fh,
    const float* __restrict__ b1bi, const float* __restrict__ b1bh,
    const float* __restrict__ b2fi, const float* __restrict__ b2fh,
    const float* __restrict__ b2bi, const float* __restrict__ b2bh,
    const float* __restrict__ feat, const float* __restrict__ rois,
    unsigned short* __restrict__ w12b, unsigned short* __restrict__ w22b,
    unsigned short* __restrict__ we1o, unsigned short* __restrict__ we2o,
    unsigned char* __restrict__ o8l1f, unsigned char* __restrict__ o8l1b,
    unsigned char* __restrict__ o8l2f, unsigned char* __restrict__ o8l2b,
    float* __restrict__ pb1, float* __restrict__ pb2,
    unsigned short* __restrict__ rnn) {
  int b = blockIdx.x, tid = threadIdx.x;
  if (b < 2048) {
    const float* src = (b < 1024) ? w1f : w1b;
    unsigned short* dst = w12b + (size_t)((b < 1024) ? 0 : 1048576);
    int i = (b & 1023) * 256 + tid;
    int row = i >> 8, c4 = i & 255;
    int orow = (row & 255) * 4 + (row >> 8);   // gate*256+unit -> unit*4+gate
    float4 v = ((const float4*)src)[i];
    ushort4v o; o[0]=bf16c(v.x); o[1]=bf16c(v.y); o[2]=bf16c(v.z); o[3]=bf16c(v.w);
    *(ushort4v*)(dst + (size_t)orow * 1024 + c4 * 4) = o;
  } else if (b < 2560) {
    int bb = b - 2048;
    const float* src = (bb < 256) ? w2f : w2b;
    unsigned short* dst = w22b + (size_t)((bb < 256) ? 0 : 262144);
    int i = (bb & 255) * 256 + tid;
    int row = i >> 6, c4 = i & 63;
    int orow = (row & 255) * 4 + (row >> 8);
    float4 v = ((const float4*)src)[i];
    ushort4v o; o[0]=bf16c(v.x); o[1]=bf16c(v.y); o[2]=bf16c(v.z); o[3]=bf16c(v.w);
    *(ushort4v*)(dst + (size_t)orow * 256 + c4 * 4) = o;
  } else if (b < 2688) {
    // we1: out[j][d*256 + k] = in[j][d*256 + invpi(k)], invpi(k) = (k>>6) + (k&63)*4
    int i = (b - 2560) * 256 + tid;
    int j = i >> 7, c4 = (i & 127) * 4;
    ushort4v o;
#pragma unroll
    for (int q = 0; q < 4; ++q) {
      int c = c4 + q;
      int d = c >> 8, k = c & 255;
      int u = (k >> 6) + (k & 63) * 4;
      o[q] = bf16c(we1[(size_t)j * 512 + d * 256 + u]);
    }
    ((ushort4v*)we1o)[i] = o;
  } else if (b < 2694) {
    int i = (b - 2688) * 256 + tid;
    int j = i >> 7, c4 = (i & 127) * 4;
    ushort4v o;
#pragma unroll
    for (int q = 0; q < 4; ++q) {
      int c = c4 + q;
      int d = c >> 8, k = c & 255;
      int u = (k >> 6) + (k & 63) * 4;
      o[q] = bf16c(we2[(size_t)j * 512 + d * 256 + u]);
    }
    ((ushort4v*)we2o)[i] = o;
  } else if (b < 3718) {
    int bb = b - 2694;
    int which = bb >> 8;
    const float* src = (which == 0) ? wh1f : (which == 1) ? wh1b
                     : (which == 2) ? wh2f : wh2b;
    unsigned char* dst = (which == 0) ? o8l1f : (which == 1) ? o8l1b
                       : (which == 2) ? o8l2f : o8l2b;
    int idx = (bb & 255) * 256 + tid;
    int row = idx >> 6, k4 = (idx & 63) * 4;
    const float* r = src + (size_t)row * 256;
    unsigned o = 0;
#pragma unroll
    for (int j = 0; j < 4; ++j) {
      int kp = k4 + j;
      int u = (kp >> 6) + (kp & 63) * 4;       // inverse k-permute
      o |= ((unsigned)fp8c(r[u] * 64.0f)) << (8 * j);
    }
    ((unsigned*)dst)[idx] = o;
  } else if (b < 3726) {
    int m = (b - 3718) * 256 + tid;
    int dirq = m >> 10, mloc = m & 1023;
    int r = (mloc & 3) * 256 + (mloc >> 2);
    pb1[m] = dirq ? (b1bi[r] + b1bh[r]) : (b1fi[r] + b1fh[r]);
  } else if (b < 3734) {
    int m = (b - 3726) * 256 + tid;
    int dirq = m >> 10, mloc = m & 1023;
    int r = (mloc & 3) * 256 + (mloc >> 2);
    pb2[m] = dirq ? (b2bi[r] + b2bh[r]) : (b2fi[r] + b2fh[r]);
  } else {
    // ROI max pool
    int b2 = b - 3734;
    int n = b2 >> 8, cg = b2 & 255;
    int pw = tid & 63, ph = (tid >> 6) & 1, cl = tid >> 7;
    int c = cg * 2 + cl;

    const float* r = rois + n * 5;
    int bi = (int)r[0];
    int x1 = (int)rintf(r[1] * (float)FW);
    int y1 = (int)rintf(r[2] * (float)FH);
    int x2 = (int)rintf(r[3] * (float)FW);
    int y2 = (int)rintf(r[4] * (float)FH);
    float rw = fmaxf((float)(x2 - x1 + 1), 1.0f);
    float rh = fmaxf((float)(y2 - y1 + 1), 1.0f);
    float bin_h = rh * 0.5f;
    float bin_w = rw * (1.0f / 64.0f);

    int hs = min(max((int)floorf((float)ph * bin_h) + y1, 0), FH);
    int he = min(max((int)ceilf((float)(ph + 1) * bin_h) + y1, 0), FH);
    int wst = min(max((int)floorf((float)pw * bin_w) + x1, 0), FW);
    int wen = min(max((int)ceilf((float)(pw + 1) * bin_w) + x1, 0), FW);

    float m = -1e30f;
    bool nonempty = (hs < he) && (wst < wen);
    const float* f = feat + ((size_t)bi * 512 + c) * (FH * FW);
    for (int h = hs; h < he; ++h) {
      const float* fr = f + h * FW;
      for (int w = wst; w < wen; ++w) m = fmaxf(m, fr[w]);
    }
    float out = nonempty ? m : 0.0f;
    rnn[((size_t)pw * NSEQ + n) * 1024 + c * 2 + ph] = bf16c(out);
  }
}

// ---------------- bf16 MFMA GEMM ----------------
// mode 0: Cf[m*N+n] f32; mode 1: Cb[m*N+n] bf16;
// mode 5: xg write: Cb[dir*2097152 + ((t*256+unit)*32+n)*4 + gate] = bf16(v*1024)
#define GPITCH 40
__global__ __launch_bounds__(256) void gemm_bf16(
    const unsigned short* __restrict__ A, const unsigned short* __restrict__ B,
    float* __restrict__ Cf, unsigned short* __restrict__ Cb,
    int M, int N, int K,
    const float* __restrict__ bm1, const float* __restrict__ bn, int mode) {
  __shared__ unsigned short Al[128 * GPITCH];
  __shared__ unsigned short Bl[128 * GPITCH];
  int m0 = blockIdx.y * 128, n0 = blockIdx.x * 128;
  int tid = threadIdx.x;
  int wid = tid >> 6, l = tid & 63, ln15 = l & 15, kg = l >> 4;
  int wm = wid >> 1, wn = wid & 1;

  f32x4 acc[4][4];
#pragma unroll
  for (int i = 0; i < 4; ++i)
#pragma unroll
    for (int j = 0; j < 4; ++j)
#pragma unroll
      for (int q = 0; q < 4; ++q) acc[i][j][q] = 0.0f;

  for (int k0 = 0; k0 < K; k0 += 32) {
#pragma unroll
    for (int it = 0; it < 2; ++it) {
      int chunk = tid + it * 256;
      int row = chunk >> 2, part = chunk & 3;
      short8 va = *(const short8*)(A + (size_t)(m0 + row) * K + k0 + part * 8);
      *(short8*)(Al + row * GPITCH + part * 8) = va;
      short8 vb;
      if (n0 + row < N) {
        vb = *(const short8*)(B + (size_t)(n0 + row) * K + k0 + part * 8);
      } else {
#pragma unroll
        for (int q = 0; q < 8; ++q) vb[q] = 0;
      }
      *(short8*)(Bl + row * GPITCH + part * 8) = vb;
    }
    __syncthreads();

    short8 a[4], b[4];
#pragma unroll
    for (int mt = 0; mt < 4; ++mt)
      a[mt] = *(const short8*)(Al + (wm * 64 + mt * 16 + ln15) * GPITCH + kg * 8);
#pragma unroll
    for (int nt = 0; nt < 4; ++nt)
      b[nt] = *(const short8*)(Bl + (wn * 64 + nt * 16 + ln15) * GPITCH + kg * 8);
#pragma unroll
    for (int mt = 0; mt < 4; ++mt)
#pragma unroll
      for (int nt = 0; nt < 4; ++nt)
        acc[mt][nt] = __builtin_amdgcn_mfma_f32_16x16x32_bf16(a[mt], b[nt], acc[mt][nt], 0, 0, 0);
    __syncthreads();
  }

  if (mode == 5) {
#pragma unroll
    for (int mt = 0; mt < 4; ++mt) {
      int mbase = m0 + wm * 64 + mt * 16 + kg * 4;
      f32x4 pbv = *(const f32x4*)(bm1 + mbase);
      int dirq = mbase >> 10;
      int unit = (mbase & 1023) >> 2;
#pragma unroll
      for (int nt = 0; nt < 4; ++nt) {
        int col = n0 + wn * 64 + nt * 16 + ln15;
        int t = col >> 5, n = col & 31;
        ushort4v q;
#pragma unroll
        for (int j = 0; j < 4; ++j)
          q[j] = bf16c((acc[mt][nt][j] + pbv[j]) * 1024.0f);
        *(ushort4v*)(Cb + (size_t)dirq * 2097152u + ((t << 8) + unit) * 128 + n * 4) = q;
      }
    }
    return;
  }

#pragma unroll
  for (int mt = 0; mt < 4; ++mt) {
#pragma unroll
    for (int j = 0; j < 4; ++j) {
      int m = m0 + wm * 64 + mt * 16 + kg * 4 + j;
      float bmv = bm1 ? bm1[m] : 0.0f;
#pragma unroll
      for (int nt = 0; nt < 4; ++nt) {
        int n = n0 + wn * 64 + nt * 16 + ln15;
        if (n < N) {
          float v = acc[mt][nt][j] + bmv;
          if (bn) v += bn[n];
          if (mode == 1) Cb[(size_t)m * N + n] = bf16c(v);
          else Cf[(size_t)m * N + n] = v;
        }
      }
    }
  }
}

// ---------------- persistent BiLSTM layer (R9-verbatim lstm_layer8) -------------
// Grid 4 blocks: dir = blk>>1, batch-half = blk&1 (16 n). 512 thr = 8 waves.
// Cell writes hcat DIRECTLY at pi-slot (store after loads are consumed -> load
// waits never include the store). __expf cell, plain __syncthreads.
__global__ __launch_bounds__(512, 2) void lstm_layer8(
    const unsigned short* __restrict__ xgb,  // [dir][t][unit][n][gate] bf16, x1024
    const unsigned char* __restrict__ w8fw,  // [1024][256] fp8 (x64), k-permuted
    const unsigned char* __restrict__ w8bw,
    unsigned short* __restrict__ hcatb) {    // [64][32][512] bf16, pi-cols
  const int dir = blockIdx.x >> 1;
  const int nbase = (blockIdx.x & 1) * 16;
  const int tid = threadIdx.x;
  const int w = tid >> 6;
  const int l = tid & 63;
  const int ln15 = l & 15;
  const int kg = l >> 4;
  const int u_wave = w * 32;

  __shared__ unsigned char h8[2][16][256];   // fp8 h (x16), k-permuted + swizzled

  const unsigned char* W8 = dir ? w8bw : w8fw;

  unsigned long long afrag[8][8];
  {
    int gate = ln15 & 3, du = ln15 >> 2;
#pragma unroll
    for (int mt = 0; mt < 8; ++mt) {
      const unsigned char* wr = W8 + (size_t)((gate << 8) + u_wave + mt * 4 + du) * 256;
#pragma unroll
      for (int kc = 0; kc < 8; ++kc)
        afrag[mt][kc] = *(const unsigned long long*)(wr + kc * 32 + kg * 8);
    }
  }

  const unsigned short* xgd = xgb + (size_t)dir * 2097152u;
  const int lane_off = (nbase + ln15) * 4;
  float cst[8] = {0.f, 0.f, 0.f, 0.f, 0.f, 0.f, 0.f, 0.f};
  f32x4 acc[8];
  ushort4v xnext[8];

  {
    int t0 = dir ? 63 : 0;
    const unsigned short* xb = xgd + (size_t)t0 * 32768 + lane_off;
#pragma unroll
    for (int mt = 0; mt < 8; ++mt)
      xnext[mt] = *(const ushort4v*)(xb + (u_wave + mt * 4 + kg) * 128);
#pragma unroll
    for (int mt = 0; mt < 8; ++mt)
#pragma unroll
      for (int j = 0; j < 4; ++j) acc[mt][j] = b2f(xnext[mt][j]);
  }

  const int swzw = (ln15 & 7) << 4;
  const int myslot = kg * 64 + w * 8;        // pi-slot of this lane's 8 h values
  const float kNI = -1.0f / 1024.0f;
  const float kP2 = 2.0f / 1024.0f;

  for (int s = 0; s < TSTEPS; ++s) {
    const int t = dir ? (63 - s) : s;
    const int p = s & 1;

    // A) issue next-step xg loads first
    if (s < TSTEPS - 1) {
      int tn2 = dir ? (t - 1) : (t + 1);
      const unsigned short* xb = xgd + (size_t)tn2 * 32768 + lane_off;
#pragma unroll
      for (int mt = 0; mt < 8; ++mt)
        xnext[mt] = *(const ushort4v*)(xb + (u_wave + mt * 4 + kg) * 128);
    }

    // B) MFMA
    if (s > 0) {
      const unsigned char* hrow = &h8[p][ln15][0];
#pragma unroll
      for (int kc = 0; kc < 8; ++kc) {
        unsigned long long hb =
            *(const unsigned long long*)(hrow + ((kc * 32 + kg * 8) ^ swzw));
#pragma unroll
        for (int mt = 0; mt < 8; ++mt)
          acc[mt] = __builtin_amdgcn_mfma_f32_16x16x32_fp8_fp8(
              (long)afrag[mt][kc], (long)hb, acc[mt], 0, 0, 0);
      }
    }

    // C) cell + fp8 LDS write + DIRECT bf16 hcat store
    {
      float hv[8];
#pragma unroll
      for (int mt = 0; mt < 8; ++mt) {
        float gi = __builtin_amdgcn_rcpf(1.0f + __expf(acc[mt][0] * kNI));
        float gf = __builtin_amdgcn_rcpf(1.0f + __expf(acc[mt][1] * kNI));
        float gg = 1.0f - 2.0f * __builtin_amdgcn_rcpf(1.0f + __expf(acc[mt][2] * kP2));
        float go = __builtin_amdgcn_rcpf(1.0f + __expf(acc[mt][3] * kNI));
        float c = gf * cst[mt] + gi * gg;
        cst[mt] = c;
        hv[mt] = go * (1.0f - 2.0f * __builtin_amdgcn_rcpf(1.0f + __expf(2.0f * c)));
      }
      unsigned d0 = pk4_fp8(hv[0] * 16.f, hv[1] * 16.f, hv[2] * 16.f, hv[3] * 16.f);
      unsigned d1 = pk4_fp8(hv[4] * 16.f, hv[5] * 16.f, hv[6] * 16.f, hv[7] * 16.f);
      unsigned long long pk = (unsigned long long)d0 | ((unsigned long long)d1 << 32);
      *(unsigned long long*)(&h8[p ^ 1][ln15][0] + (myslot ^ swzw)) = pk;

      uint4v hb16;
      hb16[0] = pk_bf16(hv[0], hv[1]);
      hb16[1] = pk_bf16(hv[2], hv[3]);
      hb16[2] = pk_bf16(hv[4], hv[5]);
      hb16[3] = pk_bf16(hv[6], hv[7]);
      *(uint4v*)(hcatb + ((size_t)t * NSEQ + nbase + ln15) * 512 + dir * 256 + myslot) = hb16;

      if (s < TSTEPS - 1) {
#pragma unroll
        for (int mt = 0; mt < 8; ++mt)
#pragma unroll
          for (int j = 0; j < 4; ++j) acc[mt][j] = b2f(xnext[mt][j]);
      }
    }

    __syncthreads();
  }
}

// ---------------- fused log-softmax + CTC loss (parallel lp precompute) ----------
#define CTC_S 17
__global__ __launch_bounds__(576) void ctc_kernel(
    const float* __restrict__ preds,   // [64][32][12]
    const int* __restrict__ text,      // [256]
    const int* __restrict__ text_len,  // [32]
    float* __restrict__ out) {
  __shared__ float lp[TSTEPS][NSEQ][12];     // 96KB normalized log-probs
  __shared__ float alpha[2][NSEQ][CTC_S];
  __shared__ int ext[NSEQ][CTC_S];
  __shared__ unsigned char allow[NSEQ][CTC_S];
  __shared__ unsigned char validm[NSEQ][CTC_S];
  __shared__ int tlsh[NSEQ];
  __shared__ float logp_sh[NSEQ];

  int tid = threadIdx.x;

  // phase 1: parallel log-softmax for all 2048 rows
  for (int r = tid; r < TSTEPS * NSEQ; r += 576) {
    const float* p = preds + (size_t)r * 12;
    float mx = p[0];
#pragma unroll
    for (int k = 1; k < 12; ++k) mx = fmaxf(mx, p[k]);
    float ssum = 0.f;
#pragma unroll
    for (int k = 0; k < 12; ++k) ssum += __expf(p[k] - mx);
    float ls = mx + __logf(ssum);
    int t = r >> 5, b = r & 31;
#pragma unroll
    for (int k = 0; k < 12; ++k) lp[t][b][k] = p[k] - ls;
  }
  if (tid < NSEQ) tlsh[tid] = text_len[tid];
  __syncthreads();

  int b = tid & 31, sIdx = tid >> 5;
  bool active = sIdx < CTC_S;

  if (active) {
    int tl = tlsh[b];
    int off = 0;
    for (int i = 0; i < b; ++i) off += tlsh[i];
    int e = 0;
    if (sIdx & 1) {
      int lbl = (sIdx - 1) >> 1;
      int idx = off + lbl;
      if (idx > 255) idx = 255;
      e = (lbl < tl) ? text[idx] : 0;
    }
    ext[b][sIdx] = e;
    validm[b][sIdx] = (sIdx < 2 * tl + 1) ? 1 : 0;
  }
  __syncthreads();
  if (active) {
    int e = ext[b][sIdx];
    bool same2 = (sIdx >= 2) && (e == ext[b][sIdx - 2]);
    allow[b][sIdx] = ((sIdx >= 2) && (e != 0) && !same2) ? 1 : 0;
    float a = -1e30f;
    if (sIdx == 0) a = lp[0][b][0];
    else if (sIdx == 1 && tlsh[b] > 0) a = lp[0][b][ext[b][1]];
    alpha[0][b][sIdx] = a;
  }
  __syncthreads();

  for (int t = 1; t < TSTEPS; ++t) {
    int cur = (t - 1) & 1, nxt = t & 1;
    if (active) {
      float a = alpha[cur][b][sIdx];
      float a1 = (sIdx >= 1) ? alpha[cur][b][sIdx - 1] : -1e30f;
      float a2 = (sIdx >= 2 && allow[b][sIdx]) ? alpha[cur][b][sIdx - 2] : -1e30f;
      float m = fmaxf(a, fmaxf(a1, a2));
      float ssum = __expf(a - m) + __expf(a1 - m) + __expf(a2 - m);
      float nv = m + __logf(ssum) + lp[t][b][ext[b][sIdx]];
      alpha[nxt][b][sIdx] = validm[b][sIdx] ? nv : -1e30f;
    }
    __syncthreads();
  }

  if (tid < NSEQ) {
    int tl = tlsh[b];
    float a1 = alpha[1][b][2 * tl];
    float a2 = (tl > 0) ? alpha[1][b][2 * tl - 1] : -1e30f;
    float m = fmaxf(a1, a2);
    logp_sh[b] = m + __logf(__expf(a1 - m) + __expf(a2 - m));
  }
  __syncthreads();
  if (tid == 0) {
    float ssum = 0.f;
    for (int i = 0; i < NSEQ; ++i) ssum += logp_sh[i];
    out[0] = -ssum / (float)NSEQ;
  }
}

// ---------------- launch ----------------
extern "C" void kernel_launch(void* const* d_in, const int* in_sizes, int n_in,
                              void* d_out, int out_size, void* d_ws, size_t ws_size,
                              hipStream_t stream) {
  (void)in_sizes; (void)n_in; (void)out_size; (void)ws_size;
  const float* base_feat = (const float*)d_in[0];
  const int* text = (const int*)d_in[1];
  const int* text_len = (const int*)d_in[2];
  const float* rois = (const float*)d_in[3];
  const float* l1_fw_W_ih = (const float*)d_in[4];
  const float* l1_fw_W_hh = (const float*)d_in[5];
  const float* l1_fw_b_ih = (const float*)d_in[6];
  const float* l1_fw_b_hh = (const float*)d_in[7];
  const float* l1_bw_W_ih = (const float*)d_in[8];
  const float* l1_bw_W_hh = (const float*)d_in[9];
  const float* l1_bw_b_ih = (const float*)d_in[10];
  const float* l1_bw_b_hh = (const float*)d_in[11];
  const float* l2_fw_W_ih = (const float*)d_in[12];
  const float* l2_fw_W_hh = (const float*)d_in[13];
  const float* l2_fw_b_ih = (const float*)d_in[14];
  const float* l2_fw_b_hh = (const float*)d_in[15];
  const float* l2_bw_W_ih = (const float*)d_in[16];
  const float* l2_bw_W_hh = (const float*)d_in[17];
  const float* l2_bw_b_ih = (const float*)d_in[18];
  const float* l2_bw_b_hh = (const float*)d_in[19];
  const float* W_emb1 = (const float*)d_in[20];
  const float* b_emb1 = (const float*)d_in[21];
  const float* W_emb2 = (const float*)d_in[22];
  const float* b_emb2 = (const float*)d_in[23];

  float* ws = (float*)d_ws;
  unsigned short* xgb  = (unsigned short*)(ws + OFF_XGB);
  unsigned short* rnnb = (unsigned short*)(ws + OFF_RNNB);
  unsigned short* w12b = (unsigned short*)(ws + OFF_W12B);
  unsigned short* w22b = (unsigned short*)(ws + OFF_W22B);
  unsigned short* we1b = (unsigned short*)(ws + OFF_WE1B);
  unsigned short* we2b = (unsigned short*)(ws + OFF_WE2B);
  float* pb1 = ws + OFF_PB1;
  float* pb2 = ws + OFF_PB2;
  unsigned char* w8l1f = (unsigned char*)(ws + OFF_W8L1F);
  unsigned char* w8l1b = (unsigned char*)(ws + OFF_W8L1B);
  unsigned char* w8l2f = (unsigned char*)(ws + OFF_W8L2F);
  unsigned char* w8l2b = (unsigned char*)(ws + OFF_W8L2B);
  unsigned short* hcb1 = (unsigned short*)(ws + OFF_HCB1);
  unsigned short* hcb2 = (unsigned short*)(ws + OFF_HCB2);
  unsigned short* h1b  = (unsigned short*)(ws + OFF_H1B);
  float* preds = ws + OFF_PREDS;

  // 0) all weight/bias prep + ROI pool in one launch
  prep_kernel<<<11926, 256, 0, stream>>>(
      l1_fw_W_ih, l1_bw_W_ih, l2_fw_W_ih, l2_bw_W_ih, W_emb1, W_emb2,
      l1_fw_W_hh, l1_bw_W_hh, l2_fw_W_hh, l2_bw_W_hh,
      l1_fw_b_ih, l1_fw_b_hh, l1_bw_b_ih, l1_bw_b_hh,
      l2_fw_b_ih, l2_fw_b_hh, l2_bw_b_ih, l2_bw_b_hh,
      base_feat, rois,
      w12b, w22b, we1b, we2b, w8l1f, w8l1b, w8l2f, w8l2b, pb1, pb2, rnnb);

  // 1) xg layer1, both dirs in one launch (mode 5)
  gemm_bf16<<<dim3(16, 16), 256, 0, stream>>>(w12b, rnnb, nullptr, xgb,
      2048, 2048, 1024, pb1, nullptr, 5);

  // 2) layer-1 recurrence
  lstm_layer8<<<4, 512, 0, stream>>>(xgb, w8l1f, w8l1b, hcb1);

  // 3) h1 = hcat1 @ W_emb1^T + b_emb1 -> bf16 [2048][256] (pi-cols cancel)
  gemm_bf16<<<dim3(2, 16), 256, 0, stream>>>(hcb1, we1b, nullptr, h1b,
      2048, 256, 512, nullptr, b_emb1, 1);

  // 4) xg layer2 (mode 5)
  gemm_bf16<<<dim3(16, 16), 256, 0, stream>>>(w22b, h1b, nullptr, xgb,
      2048, 2048, 256, pb2, nullptr, 5);

  // 5) layer-2 recurrence
  lstm_layer8<<<4, 512, 0, stream>>>(xgb, w8l2f, w8l2b, hcb2);

  // 6) preds = hcat2 @ W_emb2^T + b_emb2 (f32, N=12 guarded, pi-cols cancel)
  gemm_bf16<<<dim3(1, 16), 256, 0, stream>>>(hcb2, we2b, preds, nullptr,
      2048, 12, 512, nullptr, b_emb2, 0);

  // 7) log-softmax + CTC
  ctc_kernel<<<1, 576, 0, stream>>>(preds, text, text_len, (float*)d_out);
}

// Round 14
// 419.708 us; speedup vs baseline: 1.2539x; 1.0638x over previous
//
#include <hip/hip_runtime.h>
#include <math.h>

// ---------------- problem constants ----------------
#define TSTEPS 64
#define NSEQ   32
#define FH     40
#define FW     160

// ---------------- workspace layout (float units) ----------------
#define OFF_XGB    0u            // [2][64 t][256 unit][32 n][4 gate] bf16, x1024
#define OFF_RNNB   2097152u      // [2048 tn][1024] bf16
#define OFF_W12B   3145728u      // W_ih l1 bf16, row-permuted unit*4+gate, [2048][1024]
#define OFF_W22B   4194304u      // W_ih l2 bf16 permuted [2048][256]
#define OFF_WE1B   4456448u      // W_emb1 bf16 [256][512], COLUMNS pi-permuted
#define OFF_WE2B   4521984u      // W_emb2 bf16 [12][512], COLUMNS pi-permuted
#define OFF_PB1    4525056u      // combined permuted bias l1 [2048] f32
#define OFF_PB2    4527104u      // combined permuted bias l2 [2048] f32
#define OFF_W8L1F  4529152u      // W_hh fp8 (x64) k-permuted [1024][256]
#define OFF_W8L1B  4594688u
#define OFF_W8L2F  4660224u
#define OFF_W8L2B  4725760u
#define OFF_HCB1   4791296u      // hcat1 bf16 [2048][512] (pi-permuted cols)
#define OFF_HCB2   5315584u
#define OFF_H1B    5839872u      // h1 bf16 [2048][256]
#define OFF_PREDS  6102016u      // [2048][12] f32

typedef __attribute__((ext_vector_type(8))) short short8;
typedef __attribute__((ext_vector_type(4))) float f32x4;
typedef __attribute__((ext_vector_type(4))) unsigned short ushort4v;
typedef __attribute__((ext_vector_type(4))) unsigned uint4v;

static __device__ inline unsigned short bf16c(float x) {
  union { float f; unsigned u; } v; v.f = x;
  unsigned r = v.u + 0x7fff + ((v.u >> 16) & 1);   // RNE
  return (unsigned short)(r >> 16);
}
static __device__ inline float b2f(unsigned short u) {
  union { unsigned u; float f; } v; v.u = ((unsigned)u) << 16;
  return v.f;
}
static __device__ inline unsigned pk_bf16(float lo, float hi) {
  unsigned r;
  asm("v_cvt_pk_bf16_f32 %0, %1, %2" : "=v"(r) : "v"(lo), "v"(hi));
  return r;
}
// f32 -> fp8 e4m3fn (OCP): RNE, saturate, flush subnormals
static __device__ inline unsigned char fp8c(float x) {
  union { float f; unsigned u; } v; v.f = x;
  unsigned s = (v.u >> 24) & 0x80;
  float ax = fabsf(x);
  if (ax < 0.015625f) return (unsigned char)s;
  if (ax >= 448.0f) return (unsigned char)(s | 0x7e);
  unsigned e = (v.u >> 23) & 0xff;
  unsigned m = v.u & 0x7fffff;
  unsigned r = m + 0x7ffff + ((m >> 20) & 1);
  if (r >> 23) { e += 1; r = 0; }
  unsigned m3 = (r >> 20) & 7;
  int ee = (int)e - 127 + 7;
  if (ee > 15) return (unsigned char)(s | 0x7e);
  return (unsigned char)(s | (ee << 3) | m3);
}
static __device__ inline unsigned pk4_fp8(float a, float b, float c, float d) {
#if __has_builtin(__builtin_amdgcn_cvt_pk_fp8_f32)
  int r = __builtin_amdgcn_cvt_pk_fp8_f32(a, b, 0, false);
  r = __builtin_amdgcn_cvt_pk_fp8_f32(c, d, r, true);
  return (unsigned)r;
#else
  return (unsigned)fp8c(a) | ((unsigned)fp8c(b) << 8)
       | ((unsigned)fp8c(c) << 16) | ((unsigned)fp8c(d) << 24);
#endif
}

// ---------------- single prep kernel (weights/biases + ROI max pool) ----------------
__global__ __launch_bounds__(256) void prep_kernel(
    const float* __restrict__ w1f, const float* __restrict__ w1b,
    const float* __restrict__ w2f, const float* __restrict__ w2b,
    const float* __restrict__ we1, const float* __restrict__ we2,
    const float* __restrict__ wh1f, const float* __restrict__ wh1b,
    const float* __restrict__ wh2f, const float* __restrict__ wh2b,
    const float* __restrict__ b1fi, const float* __restrict__ b1fh,
    const float* __restrict__ b1bi, const float* __restrict__ b1bh,
    const float* __restrict__ b2fi, const float* __restrict__ b2fh,
    const float* __restrict__ b2bi, const float* __restrict__ b2bh,
    const float* __restrict__ feat, const float* __restrict__ rois,
    unsigned short* __restrict__ w12b, unsigned short* __restrict__ w22b,
    unsigned short* __restrict__ we1o, unsigned short* __restrict__ we2o,
    unsigned char* __restrict__ o8l1f, unsigned char* __restrict__ o8l1b,
    unsigned char* __restrict__ o8l2f, unsigned char* __restrict__ o8l2b,
    float* __restrict__ pb1, float* __restrict__ pb2,
    unsigned short* __restrict__ rnn) {
  int b = blockIdx.x, tid = threadIdx.x;
  if (b < 2048) {
    const float* src = (b < 1024) ? w1f : w1b;
    unsigned short* dst = w12b + (size_t)((b < 1024) ? 0 : 1048576);
    int i = (b & 1023) * 256 + tid;
    int row = i >> 8, c4 = i & 255;
    int orow = (row & 255) * 4 + (row >> 8);   // gate*256+unit -> unit*4+gate
    float4 v = ((const float4*)src)[i];
    ushort4v o; o[0]=bf16c(v.x); o[1]=bf16c(v.y); o[2]=bf16c(v.z); o[3]=bf16c(v.w);
    *(ushort4v*)(dst + (size_t)orow * 1024 + c4 * 4) = o;
  } else if (b < 2560) {
    int bb = b - 2048;
    const float* src = (bb < 256) ? w2f : w2b;
    unsigned short* dst = w22b + (size_t)((bb < 256) ? 0 : 262144);
    int i = (bb & 255) * 256 + tid;
    int row = i >> 6, c4 = i & 63;
    int orow = (row & 255) * 4 + (row >> 8);
    float4 v = ((const float4*)src)[i];
    ushort4v o; o[0]=bf16c(v.x); o[1]=bf16c(v.y); o[2]=bf16c(v.z); o[3]=bf16c(v.w);
    *(ushort4v*)(dst + (size_t)orow * 256 + c4 * 4) = o;
  } else if (b < 2688) {
    int i = (b - 2560) * 256 + tid;
    int j = i >> 7, c4 = (i & 127) * 4;
    ushort4v o;
#pragma unroll
    for (int q = 0; q < 4; ++q) {
      int c = c4 + q;
      int d = c >> 8, k = c & 255;
      int u = (k >> 6) + (k & 63) * 4;
      o[q] = bf16c(we1[(size_t)j * 512 + d * 256 + u]);
    }
    ((ushort4v*)we1o)[i] = o;
  } else if (b < 2694) {
    int i = (b - 2688) * 256 + tid;
    int j = i >> 7, c4 = (i & 127) * 4;
    ushort4v o;
#pragma unroll
    for (int q = 0; q < 4; ++q) {
      int c = c4 + q;
      int d = c >> 8, k = c & 255;
      int u = (k >> 6) + (k & 63) * 4;
      o[q] = bf16c(we2[(size_t)j * 512 + d * 256 + u]);
    }
    ((ushort4v*)we2o)[i] = o;
  } else if (b < 3718) {
    int bb = b - 2694;
    int which = bb >> 8;
    const float* src = (which == 0) ? wh1f : (which == 1) ? wh1b
                     : (which == 2) ? wh2f : wh2b;
    unsigned char* dst = (which == 0) ? o8l1f : (which == 1) ? o8l1b
                       : (which == 2) ? o8l2f : o8l2b;
    int idx = (bb & 255) * 256 + tid;
    int row = idx >> 6, k4 = (idx & 63) * 4;
    const float* r = src + (size_t)row * 256;
    unsigned o = 0;
#pragma unroll
    for (int j = 0; j < 4; ++j) {
      int kp = k4 + j;
      int u = (kp >> 6) + (kp & 63) * 4;       // inverse k-permute
      o |= ((unsigned)fp8c(r[u] * 64.0f)) << (8 * j);
    }
    ((unsigned*)dst)[idx] = o;
  } else if (b < 3726) {
    int m = (b - 3718) * 256 + tid;
    int dirq = m >> 10, mloc = m & 1023;
    int r = (mloc & 3) * 256 + (mloc >> 2);
    pb1[m] = dirq ? (b1bi[r] + b1bh[r]) : (b1fi[r] + b1fh[r]);
  } else if (b < 3734) {
    int m = (b - 3726) * 256 + tid;
    int dirq = m >> 10, mloc = m & 1023;
    int r = (mloc & 3) * 256 + (mloc >> 2);
    pb2[m] = dirq ? (b2bi[r] + b2bh[r]) : (b2fi[r] + b2fh[r]);
  } else {
    // ROI max pool
    int b2 = b - 3734;
    int n = b2 >> 8, cg = b2 & 255;
    int pw = tid & 63, ph = (tid >> 6) & 1, cl = tid >> 7;
    int c = cg * 2 + cl;

    const float* r = rois + n * 5;
    int bi = (int)r[0];
    int x1 = (int)rintf(r[1] * (float)FW);
    int y1 = (int)rintf(r[2] * (float)FH);
    int x2 = (int)rintf(r[3] * (float)FW);
    int y2 = (int)rintf(r[4] * (float)FH);
    float rw = fmaxf((float)(x2 - x1 + 1), 1.0f);
    float rh = fmaxf((float)(y2 - y1 + 1), 1.0f);
    float bin_h = rh * 0.5f;
    float bin_w = rw * (1.0f / 64.0f);

    int hs = min(max((int)floorf((float)ph * bin_h) + y1, 0), FH);
    int he = min(max((int)ceilf((float)(ph + 1) * bin_h) + y1, 0), FH);
    int wst = min(max((int)floorf((float)pw * bin_w) + x1, 0), FW);
    int wen = min(max((int)ceilf((float)(pw + 1) * bin_w) + x1, 0), FW);

    float m = -1e30f;
    bool nonempty = (hs < he) && (wst < wen);
    const float* f = feat + ((size_t)bi * 512 + c) * (FH * FW);
    for (int h = hs; h < he; ++h) {
      const float* fr = f + h * FW;
      for (int w = wst; w < wen; ++w) m = fmaxf(m, fr[w]);
    }
    float out = nonempty ? m : 0.0f;
    rnn[((size_t)pw * NSEQ + n) * 1024 + c * 2 + ph] = bf16c(out);
  }
}

// ---------------- bf16 MFMA GEMM, 128m x 64n tile (2 blocks/CU) ----------------
// mode 0: Cf[m*N+n] f32; mode 1: Cb[m*N+n] bf16;
// mode 5: xg write: Cb[dir*2097152 + ((t*256+unit)*32+n)*4 + gate] = bf16(v*1024)
#define GPITCH 40
__global__ __launch_bounds__(256) void gemm_bf16(
    const unsigned short* __restrict__ A, const unsigned short* __restrict__ B,
    float* __restrict__ Cf, unsigned short* __restrict__ Cb,
    int M, int N, int K,
    const float* __restrict__ bm1, const float* __restrict__ bn, int mode) {
  __shared__ unsigned short Al[128 * GPITCH];
  __shared__ unsigned short Bl[64 * GPITCH];
  int m0 = blockIdx.y * 128, n0 = blockIdx.x * 64;
  int tid = threadIdx.x;
  int wid = tid >> 6, l = tid & 63, ln15 = l & 15, kg = l >> 4;
  int wm = wid >> 1, wn = wid & 1;   // 2x2 waves: 64m x 32n each

  f32x4 acc[4][2];
#pragma unroll
  for (int i = 0; i < 4; ++i)
#pragma unroll
    for (int j = 0; j < 2; ++j)
#pragma unroll
      for (int q = 0; q < 4; ++q) acc[i][j][q] = 0.0f;

  for (int k0 = 0; k0 < K; k0 += 32) {
    // A: 128 rows x 32 k -> 512 chunks (2/thread)
#pragma unroll
    for (int it = 0; it < 2; ++it) {
      int chunk = tid + it * 256;
      int row = chunk >> 2, part = chunk & 3;
      short8 va = *(const short8*)(A + (size_t)(m0 + row) * K + k0 + part * 8);
      *(short8*)(Al + row * GPITCH + part * 8) = va;
    }
    // B: 64 rows x 32 k -> 256 chunks (1/thread)
    {
      int row = tid >> 2, part = tid & 3;
      short8 vb;
      if (n0 + row < N) {
        vb = *(const short8*)(B + (size_t)(n0 + row) * K + k0 + part * 8);
      } else {
#pragma unroll
        for (int q = 0; q < 8; ++q) vb[q] = 0;
      }
      *(short8*)(Bl + row * GPITCH + part * 8) = vb;
    }
    __syncthreads();

    short8 a[4], b[2];
#pragma unroll
    for (int mt = 0; mt < 4; ++mt)
      a[mt] = *(const short8*)(Al + (wm * 64 + mt * 16 + ln15) * GPITCH + kg * 8);
#pragma unroll
    for (int nt = 0; nt < 2; ++nt)
      b[nt] = *(const short8*)(Bl + (wn * 32 + nt * 16 + ln15) * GPITCH + kg * 8);
#pragma unroll
    for (int mt = 0; mt < 4; ++mt)
#pragma unroll
      for (int nt = 0; nt < 2; ++nt)
        acc[mt][nt] = __builtin_amdgcn_mfma_f32_16x16x32_bf16(a[mt], b[nt], acc[mt][nt], 0, 0, 0);
    __syncthreads();
  }

  if (mode == 5) {
#pragma unroll
    for (int mt = 0; mt < 4; ++mt) {
      int mbase = m0 + wm * 64 + mt * 16 + kg * 4;
      f32x4 pbv = *(const f32x4*)(bm1 + mbase);
      int dirq = mbase >> 10;
      int unit = (mbase & 1023) >> 2;
#pragma unroll
      for (int nt = 0; nt < 2; ++nt) {
        int col = n0 + wn * 32 + nt * 16 + ln15;
        int t = col >> 5, n = col & 31;
        ushort4v q;
#pragma unroll
        for (int j = 0; j < 4; ++j)
          q[j] = bf16c((acc[mt][nt][j] + pbv[j]) * 1024.0f);
        *(ushort4v*)(Cb + (size_t)dirq * 2097152u + ((t << 8) + unit) * 128 + n * 4) = q;
      }
    }
    return;
  }

#pragma unroll
  for (int mt = 0; mt < 4; ++mt) {
#pragma unroll
    for (int j = 0; j < 4; ++j) {
      int m = m0 + wm * 64 + mt * 16 + kg * 4 + j;
      float bmv = bm1 ? bm1[m] : 0.0f;
#pragma unroll
      for (int nt = 0; nt < 2; ++nt) {
        int n = n0 + wn * 32 + nt * 16 + ln15;
        if (n < N) {
          float v = acc[mt][nt][j] + bmv;
          if (bn) v += bn[n];
          if (mode == 1) Cb[(size_t)m * N + n] = bf16c(v);
          else Cf[(size_t)m * N + n] = v;
        }
      }
    }
  }
}

// ---------------- persistent BiLSTM layer (R9-verbatim lstm_layer8) -------------
__global__ __launch_bounds__(512, 2) void lstm_layer8(
    const unsigned short* __restrict__ xgb,  // [dir][t][unit][n][gate] bf16, x1024
    const unsigned char* __restrict__ w8fw,  // [1024][256] fp8 (x64), k-permuted
    const unsigned char* __restrict__ w8bw,
    unsigned short* __restrict__ hcatb) {    // [64][32][512] bf16, pi-cols
  const int dir = blockIdx.x >> 1;
  const int nbase = (blockIdx.x & 1) * 16;
  const int tid = threadIdx.x;
  const int w = tid >> 6;
  const int l = tid & 63;
  const int ln15 = l & 15;
  const int kg = l >> 4;
  const int u_wave = w * 32;

  __shared__ unsigned char h8[2][16][256];   // fp8 h (x16), k-permuted + swizzled

  const unsigned char* W8 = dir ? w8bw : w8fw;

  unsigned long long afrag[8][8];
  {
    int gate = ln15 & 3, du = ln15 >> 2;
#pragma unroll
    for (int mt = 0; mt < 8; ++mt) {
      const unsigned char* wr = W8 + (size_t)((gate << 8) + u_wave + mt * 4 + du) * 256;
#pragma unroll
      for (int kc = 0; kc < 8; ++kc)
        afrag[mt][kc] = *(const unsigned long long*)(wr + kc * 32 + kg * 8);
    }
  }

  const unsigned short* xgd = xgb + (size_t)dir * 2097152u;
  const int lane_off = (nbase + ln15) * 4;
  float cst[8] = {0.f, 0.f, 0.f, 0.f, 0.f, 0.f, 0.f, 0.f};
  f32x4 acc[8];
  ushort4v xnext[8];

  {
    int t0 = dir ? 63 : 0;
    const unsigned short* xb = xgd + (size_t)t0 * 32768 + lane_off;
#pragma unroll
    for (int mt = 0; mt < 8; ++mt)
      xnext[mt] = *(const ushort4v*)(xb + (u_wave + mt * 4 + kg) * 128);
#pragma unroll
    for (int mt = 0; mt < 8; ++mt)
#pragma unroll
      for (int j = 0; j < 4; ++j) acc[mt][j] = b2f(xnext[mt][j]);
  }

  const int swzw = (ln15 & 7) << 4;
  const int myslot = kg * 64 + w * 8;
  const float kNI = -1.0f / 1024.0f;
  const float kP2 = 2.0f / 1024.0f;

  for (int s = 0; s < TSTEPS; ++s) {
    const int t = dir ? (63 - s) : s;
    const int p = s & 1;

    if (s < TSTEPS - 1) {
      int tn2 = dir ? (t - 1) : (t + 1);
      const unsigned short* xb = xgd + (size_t)tn2 * 32768 + lane_off;
#pragma unroll
      for (int mt = 0; mt < 8; ++mt)
        xnext[mt] = *(const ushort4v*)(xb + (u_wave + mt * 4 + kg) * 128);
    }

    if (s > 0) {
      const unsigned char* hrow = &h8[p][ln15][0];
#pragma unroll
      for (int kc = 0; kc < 8; ++kc) {
        unsigned long long hb =
            *(const unsigned long long*)(hrow + ((kc * 32 + kg * 8) ^ swzw));
#pragma unroll
        for (int mt = 0; mt < 8; ++mt)
          acc[mt] = __builtin_amdgcn_mfma_f32_16x16x32_fp8_fp8(
              (long)afrag[mt][kc], (long)hb, acc[mt], 0, 0, 0);
      }
    }

    {
      float hv[8];
#pragma unroll
      for (int mt = 0; mt < 8; ++mt) {
        float gi = __builtin_amdgcn_rcpf(1.0f + __expf(acc[mt][0] * kNI));
        float gf = __builtin_amdgcn_rcpf(1.0f + __expf(acc[mt][1] * kNI));
        float gg = 1.0f - 2.0f * __builtin_amdgcn_rcpf(1.0f + __expf(acc[mt][2] * kP2));
        float go = __builtin_amdgcn_rcpf(1.0f + __expf(acc[mt][3] * kNI));
        float c = gf * cst[mt] + gi * gg;
        cst[mt] = c;
        hv[mt] = go * (1.0f - 2.0f * __builtin_amdgcn_rcpf(1.0f + __expf(2.0f * c)));
      }
      unsigned d0 = pk4_fp8(hv[0] * 16.f, hv[1] * 16.f, hv[2] * 16.f, hv[3] * 16.f);
      unsigned d1 = pk4_fp8(hv[4] * 16.f, hv[5] * 16.f, hv[6] * 16.f, hv[7] * 16.f);
      unsigned long long pk = (unsigned long long)d0 | ((unsigned long long)d1 << 32);
      *(unsigned long long*)(&h8[p ^ 1][ln15][0] + (myslot ^ swzw)) = pk;

      uint4v hb16;
      hb16[0] = pk_bf16(hv[0], hv[1]);
      hb16[1] = pk_bf16(hv[2], hv[3]);
      hb16[2] = pk_bf16(hv[4], hv[5]);
      hb16[3] = pk_bf16(hv[6], hv[7]);
      *(uint4v*)(hcatb + ((size_t)t * NSEQ + nbase + ln15) * 512 + dir * 256 + myslot) = hb16;

      if (s < TSTEPS - 1) {
#pragma unroll
        for (int mt = 0; mt < 8; ++mt)
#pragma unroll
          for (int j = 0; j < 4; ++j) acc[mt][j] = b2f(xnext[mt][j]);
      }
    }

    __syncthreads();
  }
}

// ---------------- CTC: parallel log-softmax + barrier-free wave scan ------------
// 1024 threads = 16 waves. Scan: wave w holds b = 2w + (lane>=32), s = lane&31
// (s<17 active); alpha in registers; alpha[s-1], alpha[s-2] via __shfl_up width 32
// (wave-lockstep -> NO barriers in the 63-step scan).
#define CTC_S 17
__global__ __launch_bounds__(1024) void ctc_kernel(
    const float* __restrict__ preds,   // [64][32][12]
    const int* __restrict__ text,      // [256]
    const int* __restrict__ text_len,  // [32]
    float* __restrict__ out) {
  __shared__ float lp[TSTEPS][NSEQ][12];     // 96KB normalized log-probs
  __shared__ int tlsh[NSEQ];
  __shared__ float alpha_f[NSEQ][CTC_S];
  __shared__ float logp_sh[NSEQ];

  int tid = threadIdx.x;

  // phase 1: parallel log-softmax (2 rows/thread)
  for (int r = tid; r < TSTEPS * NSEQ; r += 1024) {
    const float* p = preds + (size_t)r * 12;
    float mx = p[0];
#pragma unroll
    for (int k = 1; k < 12; ++k) mx = fmaxf(mx, p[k]);
    float ssum = 0.f;
#pragma unroll
    for (int k = 0; k < 12; ++k) ssum += __expf(p[k] - mx);
    float ls = mx + __logf(ssum);
    int t = r >> 5, b = r & 31;
#pragma unroll
    for (int k = 0; k < 12; ++k) lp[t][b][k] = p[k] - ls;
  }
  if (tid < NSEQ) tlsh[tid] = text_len[tid];
  __syncthreads();

  const int wv = tid >> 6;
  const int lane = tid & 63;
  const int b = wv * 2 + (lane >> 5);
  const int s = lane & 31;
  const bool active = (s < CTC_S);

  // per-lane ext / allow / valid
  int tl = tlsh[b];
  int e = 0;
  if (active && (s & 1)) {
    int off = 0;
    for (int i = 0; i < b; ++i) off += tlsh[i];
    int lbl = (s - 1) >> 1;
    int idx = off + lbl;
    if (idx > 255) idx = 255;
    e = (lbl < tl) ? text[idx] : 0;
  }
  // allow: need ext[s-2]; get via shfl (width 32)
  int e2 = __shfl_up(e, 2, 32);
  bool allow = active && (s >= 2) && (e != 0) && (e != e2);
  bool valid = active && (s < 2 * tl + 1);

  // init t=0
  float alpha = -1e30f;
  if (active) {
    if (s == 0) alpha = lp[0][b][0];
    else if (s == 1 && tl > 0) alpha = lp[0][b][e];
  }

  // scan t = 1..63, barrier-free (wave lockstep)
  for (int t = 1; t < TSTEPS; ++t) {
    float a1 = __shfl_up(alpha, 1, 32);
    float a2 = __shfl_up(alpha, 2, 32);
    if (s < 1) a1 = -1e30f;
    if (!allow) a2 = -1e30f;
    float m = fmaxf(alpha, fmaxf(a1, a2));
    float ssum = __expf(alpha - m) + __expf(a1 - m) + __expf(a2 - m);
    float nv = m + __logf(ssum) + lp[t][b][e];
    alpha = valid ? nv : -1e30f;
  }

  if (active) alpha_f[b][s] = alpha;
  __syncthreads();

  if (tid < NSEQ) {
    int tl2 = tlsh[tid];
    float a1 = alpha_f[tid][2 * tl2];
    float a2 = (tl2 > 0) ? alpha_f[tid][2 * tl2 - 1] : -1e30f;
    float m = fmaxf(a1, a2);
    logp_sh[tid] = m + __logf(__expf(a1 - m) + __expf(a2 - m));
  }
  __syncthreads();
  if (tid == 0) {
    float ssum = 0.f;
    for (int i = 0; i < NSEQ; ++i) ssum += logp_sh[i];
    out[0] = -ssum / (float)NSEQ;
  }
}

// ---------------- launch ----------------
extern "C" void kernel_launch(void* const* d_in, const int* in_sizes, int n_in,
                              void* d_out, int out_size, void* d_ws, size_t ws_size,
                              hipStream_t stream) {
  (void)in_sizes; (void)n_in; (void)out_size; (void)ws_size;
  const float* base_feat = (const float*)d_in[0];
  const int* text = (const int*)d_in[1];
  const int* text_len = (const int*)d_in[2];
  const float* rois = (const float*)d_in[3];
  const float* l1_fw_W_ih = (const float*)d_in[4];
  const float* l1_fw_W_hh = (const float*)d_in[5];
  const float* l1_fw_b_ih = (const float*)d_in[6];
  const float* l1_fw_b_hh = (const float*)d_in[7];
  const float* l1_bw_W_ih = (const float*)d_in[8];
  const float* l1_bw_W_hh = (const float*)d_in[9];
  const float* l1_bw_b_ih = (const float*)d_in[10];
  const float* l1_bw_b_hh = (const float*)d_in[11];
  const float* l2_fw_W_ih = (const float*)d_in[12];
  const float* l2_fw_W_hh = (const float*)d_in[13];
  const float* l2_fw_b_ih = (const float*)d_in[14];
  const float* l2_fw_b_hh = (const float*)d_in[15];
  const float* l2_bw_W_ih = (const float*)d_in[16];
  const float* l2_bw_W_hh = (const float*)d_in[17];
  const float* l2_bw_b_ih = (const float*)d_in[18];
  const float* l2_bw_b_hh = (const float*)d_in[19];
  const float* W_emb1 = (const float*)d_in[20];
  const float* b_emb1 = (const float*)d_in[21];
  const float* W_emb2 = (const float*)d_in[22];
  const float* b_emb2 = (const float*)d_in[23];

  float* ws = (float*)d_ws;
  unsigned short* xgb  = (unsigned short*)(ws + OFF_XGB);
  unsigned short* rnnb = (unsigned short*)(ws + OFF_RNNB);
  unsigned short* w12b = (unsigned short*)(ws + OFF_W12B);
  unsigned short* w22b = (unsigned short*)(ws + OFF_W22B);
  unsigned short* we1b = (unsigned short*)(ws + OFF_WE1B);
  unsigned short* we2b = (unsigned short*)(ws + OFF_WE2B);
  float* pb1 = ws + OFF_PB1;
  float* pb2 = ws + OFF_PB2;
  unsigned char* w8l1f = (unsigned char*)(ws + OFF_W8L1F);
  unsigned char* w8l1b = (unsigned char*)(ws + OFF_W8L1B);
  unsigned char* w8l2f = (unsigned char*)(ws + OFF_W8L2F);
  unsigned char* w8l2b = (unsigned char*)(ws + OFF_W8L2B);
  unsigned short* hcb1 = (unsigned short*)(ws + OFF_HCB1);
  unsigned short* hcb2 = (unsigned short*)(ws + OFF_HCB2);
  unsigned short* h1b  = (unsigned short*)(ws + OFF_H1B);
  float* preds = ws + OFF_PREDS;

  // 0) all weight/bias prep + ROI pool in one launch
  prep_kernel<<<11926, 256, 0, stream>>>(
      l1_fw_W_ih, l1_bw_W_ih, l2_fw_W_ih, l2_bw_W_ih, W_emb1, W_emb2,
      l1_fw_W_hh, l1_bw_W_hh, l2_fw_W_hh, l2_bw_W_hh,
      l1_fw_b_ih, l1_fw_b_hh, l1_bw_b_ih, l1_bw_b_hh,
      l2_fw_b_ih, l2_fw_b_hh, l2_bw_b_ih, l2_bw_b_hh,
      base_feat, rois,
      w12b, w22b, we1b, we2b, w8l1f, w8l1b, w8l2f, w8l2b, pb1, pb2, rnnb);

  // 1) xg layer1 (mode 5), 128x64 tiles -> 512 blocks (2/CU)
  gemm_bf16<<<dim3(32, 16), 256, 0, stream>>>(w12b, rnnb, nullptr, xgb,
      2048, 2048, 1024, pb1, nullptr, 5);

  // 2) layer-1 recurrence
  lstm_layer8<<<4, 512, 0, stream>>>(xgb, w8l1f, w8l1b, hcb1);

  // 3) h1 = hcat1 @ W_emb1^T + b_emb1 -> bf16 [2048][256]
  gemm_bf16<<<dim3(4, 16), 256, 0, stream>>>(hcb1, we1b, nullptr, h1b,
      2048, 256, 512, nullptr, b_emb1, 1);

  // 4) xg layer2 (mode 5)
  gemm_bf16<<<dim3(32, 16), 256, 0, stream>>>(w22b, h1b, nullptr, xgb,
      2048, 2048, 256, pb2, nullptr, 5);

  // 5) layer-2 recurrence
  lstm_layer8<<<4, 512, 0, stream>>>(xgb, w8l2f, w8l2b, hcb2);

  // 6) preds = hcat2 @ W_emb2^T + b_emb2 (f32, N=12 guarded)
  gemm_bf16<<<dim3(1, 16), 256, 0, stream>>>(hcb2, we2b, preds, nullptr,
      2048, 12, 512, nullptr, b_emb2, 0);

  // 7) log-softmax + CTC (barrier-free scan)
  ctc_kernel<<<1, 1024, 0, stream>>>(preds, text, text_len, (float*)d_out);
}